// Round 6
// baseline (290.097 us; speedup 1.0000x reference)
//
#include <hip/hip_runtime.h>

#define Nn 1024

typedef __attribute__((ext_vector_type(8))) short short8v;
typedef __attribute__((ext_vector_type(4))) float floatx4;

__device__ __forceinline__ float fsilu(float v) { return v / (1.0f + __expf(-v)); }
__device__ __forceinline__ float fsig(float v)  { return 1.0f / (1.0f + __expf(-v)); }
__device__ __forceinline__ float ftanh10(float v){ return (1.0f - 2.0f / (__expf(2.0f * v) + 1.0f)) * 10.0f; }

// pack two fp32 -> one u32 of 2 bf16 (round-half-up): 2 adds + 1 v_perm
__device__ __forceinline__ unsigned pkbf(float lo, float hi) {
    unsigned a = __float_as_uint(lo) + 0x8000u;
    unsigned b = __float_as_uint(hi) + 0x8000u;
    return __builtin_amdgcn_perm(b, a, 0x07060302u);  // {b.hi16, a.hi16}
}

// Kernel A: ha = h@Wa^T + eb1 ; hb = h@Wb^T ; hn1 = h@nw1[:, :64]^T + nb1
__global__ __launch_bounds__(256) void precompute_kernel(
    const float* __restrict__ h, const float* __restrict__ ew1,
    const float* __restrict__ eb1, const float* __restrict__ nw1,
    const float* __restrict__ nb1, float* __restrict__ ha,
    float* __restrict__ hb, float* __restrict__ hn1)
{
    int t = blockIdx.x * 256 + threadIdx.x;
    int which = t >> 16;
    int rem = t & 65535;
    int i = rem >> 6, o = rem & 63;
    const float* hrow = h + i * 64;
    const float* wrow;
    float acc;
    if (which == 0)      { wrow = ew1 + o * 130;      acc = eb1[o]; }
    else if (which == 1) { wrow = ew1 + o * 130 + 64; acc = 0.0f;   }
    else                 { wrow = nw1 + o * 128;      acc = nb1[o]; }
    #pragma unroll
    for (int k = 0; k < 64; ++k) acc = fmaf(hrow[k], wrow[k], acc);
    if (which == 0)      ha[rem]  = acc;
    else if (which == 1) hb[rem]  = acc;
    else                 hn1[rem] = acc;
}

// Edge pipeline. 1024 blocks x 256 thr (4 waves); block owns node i0 = blockIdx.x,
// wave w owns j-quarter [w*256, w*256+256) in 16 chunks of 16 edges.
// T is built DIRECTLY in MFMA B-fragment layout in registers: lane (lr,g) owns
// edge lr and channels {g*8..g*8+7, 32+g*8..+7}. No LDS staging, no barriers,
// no lgkm serialization in the chunk loop.
// Both GEMMs swapped: D^T = W * T^T, output col = edge row = lane&15.
// waves_per_eu(3,4): 170-VGPR budget (no spill), 3-4 waves/EU.
__global__ __launch_bounds__(256) __attribute__((amdgpu_waves_per_eu(3, 4)))
void edge_mfma_kernel(
    const float* __restrict__ x, const float* __restrict__ Lp,
    const float* __restrict__ ha, const float* __restrict__ hb,
    const float* __restrict__ ew1, const float* __restrict__ ew2,
    const float* __restrict__ eb2, const float* __restrict__ chw,
    const float* __restrict__ chb, const float* __restrict__ aw,
    const float* __restrict__ ab, const float* __restrict__ cww,
    float* __restrict__ agg, float* __restrict__ delta)
{
    __shared__ __align__(16) float xs[Nn * 3];
    __shared__ float redagg[4][64];
    __shared__ float sdel[4][3];

    const int tid  = threadIdx.x;
    const int wave = tid >> 6, lane = tid & 63;
    const int lr = lane & 15, g = lane >> 4;
    const int i0 = blockIdx.x;
    const int jbase = wave * 256;
    const int ghi  = g >> 1;
    const int selA = (lr + ((g & 1) << 5)) << 2;   // bpermute byte addr
    const int selB = selA + 64;

    // stage x into LDS (float4)
    {
        const float4* xsrc = (const float4*)x;
        float4* xdst = (float4*)xs;
        xdst[tid] = xsrc[tid];
        xdst[tid + 256] = xsrc[tid + 256];
        xdst[tid + 512] = xsrc[tid + 512];
    }

    // weight fragments in registers (bf16): row n = lane&15, k 8-contig per g
    short8v bw2[2][4], bwc[2][4];
    #pragma unroll
    for (int kt = 0; kt < 2; ++kt)
      #pragma unroll
      for (int nt = 0; nt < 4; ++nt) {
        int n = nt * 16 + lr;
        int k0 = kt * 32 + g * 8;
        float4 lo = *(const float4*)(ew2 + n * 64 + k0);
        float4 hi = *(const float4*)(ew2 + n * 64 + k0 + 4);
        union { short8v s; unsigned u[4]; } pk;
        pk.u[0] = pkbf(lo.x, lo.y); pk.u[1] = pkbf(lo.z, lo.w);
        pk.u[2] = pkbf(hi.x, hi.y); pk.u[3] = pkbf(hi.z, hi.w);
        bw2[kt][nt] = pk.s;
        lo = *(const float4*)(chw + n * 64 + k0);
        hi = *(const float4*)(chw + n * 64 + k0 + 4);
        pk.u[0] = pkbf(lo.x, lo.y); pk.u[1] = pkbf(lo.z, lo.w);
        pk.u[2] = pkbf(hi.x, hi.y); pk.u[3] = pkbf(hi.z, hi.w);
        bwc[kt][nt] = pk.s;
      }

    // per-lane bias/weight vectors (n = nt*16 + g*4 + r)
    floatx4 ebr[4], awr[4], chbr[4], cwr[4];
    #pragma unroll
    for (int nt = 0; nt < 4; ++nt) {
      int n4 = nt * 16 + (g << 2);
      ebr[nt]  = *(const floatx4*)(eb2 + n4);
      awr[nt]  = *(const floatx4*)(aw  + n4);
      chbr[nt] = *(const floatx4*)(chb + n4);
      cwr[nt]  = *(const floatx4*)(cww + n4);
    }

    // per-lane ha / wr for this lane's 16 channels: k = kt*32 + g*8 + h*4 + e
    floatx4 har[4], wrr[4];
    #pragma unroll
    for (int kt = 0; kt < 2; ++kt)
      #pragma unroll
      for (int h = 0; h < 2; ++h) {
        int k0 = kt * 32 + g * 8 + h * 4;
        har[kt * 2 + h] = *(const floatx4*)(ha + i0 * 64 + k0);
        floatx4 wv;
        #pragma unroll
        for (int e = 0; e < 4; ++e) {
          float2 w2v = *(const float2*)(ew1 + (k0 + e) * 130 + 128);
          wv[e] = w2v.x + w2v.y;
        }
        wrr[kt * 2 + h] = wv;
      }

    const float L = Lp[0], invL = 1.0f / L;
    const float ab0 = ab[0];

    floatx4 agg4[4];
    #pragma unroll
    for (int nt = 0; nt < 4; ++nt) agg4[nt] = (floatx4){0.f, 0.f, 0.f, 0.f};
    float dp0 = 0.f, dp1 = 0.f, dp2 = 0.f;

    __syncthreads();

    const float xi0 = xs[i0 * 3 + 0], xi1 = xs[i0 * 3 + 1], xi2 = xs[i0 * 3 + 2];

    for (int jc = 0; jc < 16; ++jc) {
      const int j = jbase + jc * 16 + lr;

      // ---- geometry for edge (i0, j), per lane (4x redundant over g only) ----
      float xd0 = xi0 - xs[j * 3 + 0];
      float xd1 = xi1 - xs[j * 3 + 1];
      float xd2 = xi2 - xs[j * 3 + 2];
      float d0 = xd0 - L * floorf(fmaf(xd0, invL, 0.5f));
      float d1 = xd1 - L * floorf(fmaf(xd1, invL, 0.5f));
      float d2 = xd2 - L * floorf(fmaf(xd2, invL, 0.5f));
      float radial = d0 * d0 + d1 * d1 + d2 * d2;
      float cinv = 1.0f / (sqrtf(radial + 1e-8f) + 1.0f);
      float dx0 = d0 * cinv, dx1 = d1 * cinv, dx2 = d2 * cinv;

      // ---- build T fragment in registers: silu(ha + hb + radial*wr) -> bf16 ----
      const float* hrow = hb + j * 64 + g * 8;
      short8v tf[2];
      #pragma unroll
      for (int kt = 0; kt < 2; ++kt) {
        floatx4 h0 = *(const floatx4*)(hrow + kt * 32);
        floatx4 h1 = *(const floatx4*)(hrow + kt * 32 + 4);
        floatx4 p0, p1;
        #pragma unroll
        for (int e = 0; e < 4; ++e) {
          p0[e] = fsilu(fmaf(radial, wrr[kt * 2][e],     har[kt * 2][e])     + h0[e]);
          p1[e] = fsilu(fmaf(radial, wrr[kt * 2 + 1][e], har[kt * 2 + 1][e]) + h1[e]);
        }
        union { short8v s; unsigned u[4]; } pk;
        pk.u[0] = pkbf(p0[0], p0[1]); pk.u[1] = pkbf(p0[2], p0[3]);
        pk.u[2] = pkbf(p1[0], p1[1]); pk.u[3] = pkbf(p1[2], p1[3]);
        tf[kt] = pk.s;
      }

      // ---- GEMM1 (swapped): D1^T = ew2 * T^T ; C-init = eb2 ----
      floatx4 acc[4];
      #pragma unroll
      for (int nt = 0; nt < 4; ++nt) acc[nt] = ebr[nt];
      #pragma unroll
      for (int kt = 0; kt < 2; ++kt)
        #pragma unroll
        for (int nt = 0; nt < 4; ++nt)
          acc[nt] = __builtin_amdgcn_mfma_f32_16x16x32_bf16(bw2[kt][nt], tf[kt], acc[nt], 0, 0, 0);

      // ---- epilogue 1: silu, att (row-dot over n), e, agg ----
      float p = 0.f;
      #pragma unroll
      for (int nt = 0; nt < 4; ++nt)
        #pragma unroll
        for (int r = 0; r < 4; ++r) {
          float s = fsilu(acc[nt][r]);
          acc[nt][r] = s;
          p = fmaf(s, awr[nt][r], p);
        }
      p += __shfl_xor(p, 16); p += __shfl_xor(p, 32);
      const float att = fsig(p + ab0);

      unsigned Pq[4][2];
      #pragma unroll
      for (int nt = 0; nt < 4; ++nt) {
        float e0 = acc[nt][0] * att, e1 = acc[nt][1] * att;
        float e2 = acc[nt][2] * att, e3 = acc[nt][3] * att;
        agg4[nt][0] += e0; agg4[nt][1] += e1;
        agg4[nt][2] += e2; agg4[nt][3] += e3;
        Pq[nt][0] = pkbf(e0, e1);
        Pq[nt][1] = pkbf(e2, e3);
      }

      // ---- assemble GEMM2 B-frags (E^T) in-register via bpermute ----
      union { short8v s; int u[4]; } ef[2];
      #pragma unroll
      for (int kt2 = 0; kt2 < 2; ++kt2)
        #pragma unroll
        for (int w = 0; w < 4; ++w) {
          int sel = (w < 2) ? selA : selB;
          int v0 = __builtin_amdgcn_ds_bpermute(sel, (int)Pq[kt2 * 2][w & 1]);
          int v1 = __builtin_amdgcn_ds_bpermute(sel, (int)Pq[kt2 * 2 + 1][w & 1]);
          ef[kt2].u[w] = ghi ? v1 : v0;
        }

      // ---- GEMM2 (swapped): D2^T = chw * E^T ; C-init = chb ----
      floatx4 acc2[4];
      #pragma unroll
      for (int nt = 0; nt < 4; ++nt) acc2[nt] = chbr[nt];
      #pragma unroll
      for (int kt2 = 0; kt2 < 2; ++kt2)
        #pragma unroll
        for (int nt = 0; nt < 4; ++nt)
          acc2[nt] = __builtin_amdgcn_mfma_f32_16x16x32_bf16(bwc[kt2][nt], ef[kt2].s, acc2[nt], 0, 0, 0);

      // ---- epilogue 2: silu, cww-dot, tanh, delta ----
      float q = 0.f;
      #pragma unroll
      for (int nt = 0; nt < 4; ++nt)
        #pragma unroll
        for (int r = 0; r < 4; ++r)
          q = fmaf(fsilu(acc2[nt][r]), cwr[nt][r], q);
      q += __shfl_xor(q, 16); q += __shfl_xor(q, 32);
      const float wvv = ftanh10(q);
      if (g == 0) {
        dp0 = fmaf(dx0, wvv, dp0);
        dp1 = fmaf(dx1, wvv, dp1);
        dp2 = fmaf(dx2, wvv, dp2);
      }
    }

    // ---- final reductions: reduce over edge rows (lr) within wave ----
    #pragma unroll
    for (int nt = 0; nt < 4; ++nt)
      #pragma unroll
      for (int r = 0; r < 4; ++r) {
        float v = agg4[nt][r];
        v += __shfl_xor(v, 1); v += __shfl_xor(v, 2);
        v += __shfl_xor(v, 4); v += __shfl_xor(v, 8);
        agg4[nt][r] = v;
      }
    if (lr == 0) {
      #pragma unroll
      for (int nt = 0; nt < 4; ++nt)
        *(floatx4*)&redagg[wave][nt * 16 + (g << 2)] = agg4[nt];
    }
    dp0 += __shfl_xor(dp0, 1); dp0 += __shfl_xor(dp0, 2); dp0 += __shfl_xor(dp0, 4); dp0 += __shfl_xor(dp0, 8);
    dp1 += __shfl_xor(dp1, 1); dp1 += __shfl_xor(dp1, 2); dp1 += __shfl_xor(dp1, 4); dp1 += __shfl_xor(dp1, 8);
    dp2 += __shfl_xor(dp2, 1); dp2 += __shfl_xor(dp2, 2); dp2 += __shfl_xor(dp2, 4); dp2 += __shfl_xor(dp2, 8);
    if (lane == 0) { sdel[wave][0] = dp0; sdel[wave][1] = dp1; sdel[wave][2] = dp2; }
    __syncthreads();
    if (tid < 64)
      agg[i0 * 64 + tid] = redagg[0][tid] + redagg[1][tid] + redagg[2][tid] + redagg[3][tid];
    else if (tid < 67) {
      int d = tid - 64;
      delta[i0 * 3 + d] = sdel[0][d] + sdel[1][d] + sdel[2][d] + sdel[3][d];
    }
}

// Fused node update + x_new. 256 blocks x 256 thr; block owns 4 nodes.
__global__ __launch_bounds__(256) void node_fused_kernel(
    const float* __restrict__ h, const float* __restrict__ hn1,
    const float* __restrict__ agg, const float* __restrict__ nw1,
    const float* __restrict__ nw2, const float* __restrict__ nb2,
    const float* __restrict__ x, const float* __restrict__ delta,
    const float* __restrict__ Lp, float* __restrict__ outh,
    float* __restrict__ outx)
{
    __shared__ float sps[256];
    const int b = blockIdx.x, tid = threadIdx.x;
    const int gt = b * 256 + tid;
    const int i = gt >> 6, o = gt & 63;
    const float* arow = agg + i * 64;
    const float* wrow = nw1 + o * 128 + 64;
    float acc = hn1[gt];
    #pragma unroll
    for (int k = 0; k < 64; ++k) acc = fmaf(arow[k], wrow[k], acc);
    sps[tid] = fsilu(acc);
    __syncthreads();
    const float* srow = sps + (tid & ~63);
    const float* w2row = nw2 + o * 64;
    float acc2 = h[gt] + nb2[o];
    #pragma unroll
    for (int k = 0; k < 64; ++k) acc2 = fmaf(srow[k], w2row[k], acc2);
    outh[gt] = acc2;
    if (tid < 12) {
        int ii = b * 4 + tid / 3, d = tid % 3;
        float L = Lp[0];
        float v = x[ii * 3 + d] + delta[ii * 3 + d];
        outx[ii * 3 + d] = v - L * floorf(v / L);
    }
}

extern "C" void kernel_launch(void* const* d_in, const int* in_sizes, int n_in,
                              void* d_out, int out_size, void* d_ws, size_t ws_size,
                              hipStream_t stream) {
    const float* h   = (const float*)d_in[0];
    const float* x   = (const float*)d_in[1];
    const float* Lp  = (const float*)d_in[2];
    const float* ew1 = (const float*)d_in[3];
    const float* eb1 = (const float*)d_in[4];
    const float* ew2 = (const float*)d_in[5];
    const float* eb2 = (const float*)d_in[6];
    const float* nw1 = (const float*)d_in[7];
    const float* nb1 = (const float*)d_in[8];
    const float* nw2 = (const float*)d_in[9];
    const float* nb2 = (const float*)d_in[10];
    const float* chw = (const float*)d_in[11];
    const float* chb = (const float*)d_in[12];
    const float* cww = (const float*)d_in[13];
    const float* aw  = (const float*)d_in[14];
    const float* ab  = (const float*)d_in[15];

    float* ws    = (float*)d_ws;
    float* ha    = ws;             // 65536
    float* hb    = ws + 65536;     // 65536
    float* hn1   = ws + 131072;    // 65536
    float* agg   = ws + 196608;    // 65536
    float* delta = ws + 262144;    // 3072

    float* outh = (float*)d_out;       // 65536
    float* outx = outh + 65536;        // 3072

    precompute_kernel<<<768, 256, 0, stream>>>(h, ew1, eb1, nw1, nb1, ha, hb, hn1);
    edge_mfma_kernel<<<1024, 256, 0, stream>>>(x, Lp, ha, hb, ew1, ew2, eb2, chw, chb,
                                               aw, ab, cww, agg, delta);
    node_fused_kernel<<<256, 256, 0, stream>>>(h, hn1, agg, nw1, nw2, nb2, x, delta,
                                               Lp, outh, outx);
}

// Round 7
// 154.798 us; speedup vs baseline: 1.8740x; 1.8740x over previous
//
#include <hip/hip_runtime.h>

#define Nn 1024

typedef __attribute__((ext_vector_type(8))) short short8v;
typedef __attribute__((ext_vector_type(4))) float floatx4;

// hardware-rate reciprocal / sqrt (v_rcp_f32 / v_sqrt_f32, ~1ulp).
// Without these, plain '/' compiles to the ~10-instr IEEE div sequence —
// at ~200 divides per 16-edge chunk that was the dominant VALU cost (R5/R6).
__device__ __forceinline__ float frcp(float v)  { return __builtin_amdgcn_rcpf(v); }
__device__ __forceinline__ float fsilu(float v) { return v * frcp(1.0f + __expf(-v)); }
__device__ __forceinline__ float fsig(float v)  { return frcp(1.0f + __expf(-v)); }
__device__ __forceinline__ float ftanh10(float v){ return 10.0f - 20.0f * frcp(__expf(2.0f * v) + 1.0f); }

// pack two fp32 -> one u32 of 2 bf16 (round-half-up): 2 adds + 1 v_perm
__device__ __forceinline__ unsigned pkbf(float lo, float hi) {
    unsigned a = __float_as_uint(lo) + 0x8000u;
    unsigned b = __float_as_uint(hi) + 0x8000u;
    return __builtin_amdgcn_perm(b, a, 0x07060302u);  // {b.hi16, a.hi16}
}

// Kernel A: ha = h@Wa^T + eb1 ; hb = h@Wb^T ; hn1 = h@nw1[:, :64]^T + nb1
__global__ __launch_bounds__(256) void precompute_kernel(
    const float* __restrict__ h, const float* __restrict__ ew1,
    const float* __restrict__ eb1, const float* __restrict__ nw1,
    const float* __restrict__ nb1, float* __restrict__ ha,
    float* __restrict__ hb, float* __restrict__ hn1)
{
    int t = blockIdx.x * 256 + threadIdx.x;
    int which = t >> 16;
    int rem = t & 65535;
    int i = rem >> 6, o = rem & 63;
    const float* hrow = h + i * 64;
    const float* wrow;
    float acc;
    if (which == 0)      { wrow = ew1 + o * 130;      acc = eb1[o]; }
    else if (which == 1) { wrow = ew1 + o * 130 + 64; acc = 0.0f;   }
    else                 { wrow = nw1 + o * 128;      acc = nb1[o]; }
    #pragma unroll
    for (int k = 0; k < 64; ++k) acc = fmaf(hrow[k], wrow[k], acc);
    if (which == 0)      ha[rem]  = acc;
    else if (which == 1) hb[rem]  = acc;
    else                 hn1[rem] = acc;
}

// Edge pipeline. 256 blocks x 512 thr (8 waves), all blocks co-resident
// (lock-step j progression -> hb stays L2-hot). Wave w owns node blockIdx.x*4+(w&3)
// for j-half (w>>2): fully wave-private chunk loop, NO barriers inside.
// Both GEMMs computed swapped: D^T = W * T^T, output col = edge row = lane&15.
// waves_per_eu(2,4): min2 -> 256-reg budget (no forced spill, R4/R6 lesson);
// max4 -> allocator may fit 128 regs = 4 waves/SIMD.
__global__ __launch_bounds__(512) __attribute__((amdgpu_waves_per_eu(2, 4)))
void edge_mfma_kernel(
    const float* __restrict__ x, const float* __restrict__ Lp,
    const float* __restrict__ ha, const float* __restrict__ hb,
    const float* __restrict__ ew1, const float* __restrict__ ew2,
    const float* __restrict__ eb2, const float* __restrict__ chw,
    const float* __restrict__ chb, const float* __restrict__ aw,
    const float* __restrict__ ab, const float* __restrict__ cww,
    float* __restrict__ agg, float* __restrict__ delta)
{
    __shared__ __align__(16) char Tb[8][16 * 128];   // per-wave 16 rows x 64 bf16, XOR-swizzled
    __shared__ __align__(16) float xs[Nn * 3];
    __shared__ float dxs[8][3][16];
    __shared__ float redagg[8][64];
    __shared__ float sdel[8][3];

    const int tid  = threadIdx.x;
    const int wave = tid >> 6, lane = tid & 63;
    const int lr = lane & 15, g = lane >> 4;
    const int i0 = blockIdx.x * 4 + (wave & 3);
    const int jbase = (wave >> 2) * 512;
    const int rsub = lane >> 5;          // build: which of 2 rows
    const int kp   = (lane & 31) * 2;    // build: k-pair base (bf16 elements)
    const int ghi  = g >> 1;
    const int selA = (lr + ((g & 1) << 5)) << 2;   // bpermute byte addr
    const int selB = selA + 64;
    char* TbW = Tb[wave];

    // stage x into LDS (float4)
    {
        const float4* xsrc = (const float4*)x;
        float4* xdst = (float4*)xs;
        xdst[tid] = xsrc[tid];
        if (tid < 256) xdst[tid + 512] = xsrc[tid + 512];
    }

    // weight fragments in registers (bf16): row n = lane&15, k 8-contig per g
    short8v bw2[2][4], bwc[2][4];
    #pragma unroll
    for (int kt = 0; kt < 2; ++kt)
      #pragma unroll
      for (int nt = 0; nt < 4; ++nt) {
        int n = nt * 16 + lr;
        int k0 = kt * 32 + g * 8;
        float4 lo = *(const float4*)(ew2 + n * 64 + k0);
        float4 hi = *(const float4*)(ew2 + n * 64 + k0 + 4);
        union { short8v s; unsigned u[4]; } pk;
        pk.u[0] = pkbf(lo.x, lo.y); pk.u[1] = pkbf(lo.z, lo.w);
        pk.u[2] = pkbf(hi.x, hi.y); pk.u[3] = pkbf(hi.z, hi.w);
        bw2[kt][nt] = pk.s;
        lo = *(const float4*)(chw + n * 64 + k0);
        hi = *(const float4*)(chw + n * 64 + k0 + 4);
        pk.u[0] = pkbf(lo.x, lo.y); pk.u[1] = pkbf(lo.z, lo.w);
        pk.u[2] = pkbf(hi.x, hi.y); pk.u[3] = pkbf(hi.z, hi.w);
        bwc[kt][nt] = pk.s;
      }

    // per-lane bias/weight vectors, in registers (n = nt*16 + g*4 + r)
    floatx4 ebr[4], awr[4], chbr[4], cwr[4];
    #pragma unroll
    for (int nt = 0; nt < 4; ++nt) {
      int n4 = nt * 16 + (g << 2);
      ebr[nt]  = *(const floatx4*)(eb2 + n4);
      awr[nt]  = *(const floatx4*)(aw  + n4);
      chbr[nt] = *(const floatx4*)(chb + n4);
      cwr[nt]  = *(const floatx4*)(cww + n4);
    }

    const float L = Lp[0], invL = frcp(L);
    const float ab0 = ab[0];
    const float2 hv = *(const float2*)(ha + i0 * 64 + kp);
    const float hav0 = hv.x, hav1 = hv.y;
    const float2 w1a = *(const float2*)(ew1 + kp * 130 + 128);
    const float2 w1b = *(const float2*)(ew1 + (kp + 1) * 130 + 128);
    const float wr0 = w1a.x + w1a.y, wr1 = w1b.x + w1b.y;

    floatx4 agg4[4];
    #pragma unroll
    for (int nt = 0; nt < 4; ++nt) agg4[nt] = (floatx4){0.f, 0.f, 0.f, 0.f};
    float dp0 = 0.f, dp1 = 0.f, dp2 = 0.f;

    __syncthreads();

    const float xi0 = xs[i0 * 3 + 0], xi1 = xs[i0 * 3 + 1], xi2 = xs[i0 * 3 + 2];

    for (int jc = 0; jc < 32; ++jc) {
      // ---- build T = silu(ha + hb + radial*wr) for this wave's 16 rows ----
      #pragma unroll
      for (int it = 0; it < 8; ++it) {
        const int row = it * 2 + rsub;
        const int j = jbase + jc * 16 + row;
        float xd0 = xi0 - xs[j * 3 + 0];
        float xd1 = xi1 - xs[j * 3 + 1];
        float xd2 = xi2 - xs[j * 3 + 2];
        float d0 = xd0 - L * floorf(fmaf(xd0, invL, 0.5f));
        float d1 = xd1 - L * floorf(fmaf(xd1, invL, 0.5f));
        float d2 = xd2 - L * floorf(fmaf(xd2, invL, 0.5f));
        float radial = d0 * d0 + d1 * d1 + d2 * d2;
        float cinv = frcp(__builtin_amdgcn_sqrtf(radial + 1e-8f) + 1.0f);
        float2 hbv = *(const float2*)(hb + j * 64 + kp);
        float plo = fmaf(radial, wr0, hav0) + hbv.x;
        float phi = fmaf(radial, wr1, hav1) + hbv.y;
        unsigned pu = pkbf(fsilu(plo), fsilu(phi));
        // 16B unit holds 8 bf16: unit = kp>>3 (0..7), pair slot = (kp>>1)&3
        int unit = (kp >> 3) ^ (row & 7);
        *(unsigned*)(TbW + row * 128 + unit * 16 + (((kp >> 1) & 3) << 2)) = pu;
        if ((lane & 31) == 0) {
          dxs[wave][0][row] = d0 * cinv;
          dxs[wave][1][row] = d1 * cinv;
          dxs[wave][2][row] = d2 * cinv;
        }
      }
      // no barrier: Tb slice is wave-private

      // ---- GEMM1 (swapped): D1^T = ew2 * T^T ; C-init = eb2 ----
      short8v tf[2];
      #pragma unroll
      for (int kt = 0; kt < 2; ++kt) {
        int unit = (kt * 4 + g) ^ (lr & 7);
        tf[kt] = *(const short8v*)(TbW + lr * 128 + unit * 16);
      }
      floatx4 acc[4];
      #pragma unroll
      for (int nt = 0; nt < 4; ++nt) acc[nt] = ebr[nt];
      #pragma unroll
      for (int kt = 0; kt < 2; ++kt)
        #pragma unroll
        for (int nt = 0; nt < 4; ++nt)
          acc[nt] = __builtin_amdgcn_mfma_f32_16x16x32_bf16(bw2[kt][nt], tf[kt], acc[nt], 0, 0, 0);

      // ---- epilogue 1: silu, att (row-dot over n), e, agg ----
      float p = 0.f;
      #pragma unroll
      for (int nt = 0; nt < 4; ++nt)
        #pragma unroll
        for (int r = 0; r < 4; ++r) {
          float s = fsilu(acc[nt][r]);
          acc[nt][r] = s;
          p = fmaf(s, awr[nt][r], p);
        }
      p += __shfl_xor(p, 16); p += __shfl_xor(p, 32);
      const float att = fsig(p + ab0);

      unsigned Pq[4][2];
      #pragma unroll
      for (int nt = 0; nt < 4; ++nt) {
        float e0 = acc[nt][0] * att, e1 = acc[nt][1] * att;
        float e2 = acc[nt][2] * att, e3 = acc[nt][3] * att;
        agg4[nt][0] += e0; agg4[nt][1] += e1;
        agg4[nt][2] += e2; agg4[nt][3] += e3;
        Pq[nt][0] = pkbf(e0, e1);
        Pq[nt][1] = pkbf(e2, e3);
      }

      // ---- assemble GEMM2 B-frags (E^T) in-register via bpermute ----
      union { short8v s; int u[4]; } ef[2];
      #pragma unroll
      for (int kt2 = 0; kt2 < 2; ++kt2)
        #pragma unroll
        for (int w = 0; w < 4; ++w) {
          int sel = (w < 2) ? selA : selB;
          int v0 = __builtin_amdgcn_ds_bpermute(sel, (int)Pq[kt2 * 2][w & 1]);
          int v1 = __builtin_amdgcn_ds_bpermute(sel, (int)Pq[kt2 * 2 + 1][w & 1]);
          ef[kt2].u[w] = ghi ? v1 : v0;
        }

      // ---- GEMM2 (swapped): D2^T = chw * E^T ; C-init = chb ----
      floatx4 acc2[4];
      #pragma unroll
      for (int nt = 0; nt < 4; ++nt) acc2[nt] = chbr[nt];
      #pragma unroll
      for (int kt2 = 0; kt2 < 2; ++kt2)
        #pragma unroll
        for (int nt = 0; nt < 4; ++nt)
          acc2[nt] = __builtin_amdgcn_mfma_f32_16x16x32_bf16(bwc[kt2][nt], ef[kt2].s, acc2[nt], 0, 0, 0);

      // ---- epilogue 2: silu, cww-dot, tanh, delta ----
      float q = 0.f;
      #pragma unroll
      for (int nt = 0; nt < 4; ++nt)
        #pragma unroll
        for (int r = 0; r < 4; ++r)
          q = fmaf(fsilu(acc2[nt][r]), cwr[nt][r], q);
      q += __shfl_xor(q, 16); q += __shfl_xor(q, 32);
      const float wvv = ftanh10(q);
      if (g == 0) {
        dp0 = fmaf(dxs[wave][0][lr], wvv, dp0);
        dp1 = fmaf(dxs[wave][1][lr], wvv, dp1);
        dp2 = fmaf(dxs[wave][2][lr], wvv, dp2);
      }
    }

    // ---- final reductions: reduce over edge rows (lr) within wave ----
    #pragma unroll
    for (int nt = 0; nt < 4; ++nt)
      #pragma unroll
      for (int r = 0; r < 4; ++r) {
        float v = agg4[nt][r];
        v += __shfl_xor(v, 1); v += __shfl_xor(v, 2);
        v += __shfl_xor(v, 4); v += __shfl_xor(v, 8);
        agg4[nt][r] = v;
      }
    if (lr == 0) {
      #pragma unroll
      for (int nt = 0; nt < 4; ++nt)
        *(floatx4*)&redagg[wave][nt * 16 + (g << 2)] = agg4[nt];
    }
    dp0 += __shfl_xor(dp0, 1); dp0 += __shfl_xor(dp0, 2); dp0 += __shfl_xor(dp0, 4); dp0 += __shfl_xor(dp0, 8);
    dp1 += __shfl_xor(dp1, 1); dp1 += __shfl_xor(dp1, 2); dp1 += __shfl_xor(dp1, 4); dp1 += __shfl_xor(dp1, 8);
    dp2 += __shfl_xor(dp2, 1); dp2 += __shfl_xor(dp2, 2); dp2 += __shfl_xor(dp2, 4); dp2 += __shfl_xor(dp2, 8);
    if (lane == 0) { sdel[wave][0] = dp0; sdel[wave][1] = dp1; sdel[wave][2] = dp2; }
    __syncthreads();
    if (tid < 256) {
      int a = tid >> 6, n = tid & 63;
      agg[(blockIdx.x * 4 + a) * 64 + n] = redagg[a][n] + redagg[a + 4][n];
    }
    if (tid < 12) {
      int a = tid / 3, d = tid % 3;
      delta[(blockIdx.x * 4 + a) * 3 + d] = sdel[a][d] + sdel[a + 4][d];
    }
}

// Fused node update + x_new. 256 blocks x 256 thr; block owns 4 nodes.
__global__ __launch_bounds__(256) void node_fused_kernel(
    const float* __restrict__ h, const float* __restrict__ hn1,
    const float* __restrict__ agg, const float* __restrict__ nw1,
    const float* __restrict__ nw2, const float* __restrict__ nb2,
    const float* __restrict__ x, const float* __restrict__ delta,
    const float* __restrict__ Lp, float* __restrict__ outh,
    float* __restrict__ outx)
{
    __shared__ float sps[256];
    const int b = blockIdx.x, tid = threadIdx.x;
    const int gt = b * 256 + tid;
    const int i = gt >> 6, o = gt & 63;
    const float* arow = agg + i * 64;
    const float* wrow = nw1 + o * 128 + 64;
    float acc = hn1[gt];
    #pragma unroll
    for (int k = 0; k < 64; ++k) acc = fmaf(arow[k], wrow[k], acc);
    sps[tid] = fsilu(acc);
    __syncthreads();
    const float* srow = sps + (tid & ~63);
    const float* w2row = nw2 + o * 64;
    float acc2 = h[gt] + nb2[o];
    #pragma unroll
    for (int k = 0; k < 64; ++k) acc2 = fmaf(srow[k], w2row[k], acc2);
    outh[gt] = acc2;
    if (tid < 12) {
        int ii = b * 4 + tid / 3, d = tid % 3;
        float L = Lp[0];
        float v = x[ii * 3 + d] + delta[ii * 3 + d];
        outx[ii * 3 + d] = v - L * floorf(v * frcp(L));
    }
}

extern "C" void kernel_launch(void* const* d_in, const int* in_sizes, int n_in,
                              void* d_out, int out_size, void* d_ws, size_t ws_size,
                              hipStream_t stream) {
    const float* h   = (const float*)d_in[0];
    const float* x   = (const float*)d_in[1];
    const float* Lp  = (const float*)d_in[2];
    const float* ew1 = (const float*)d_in[3];
    const float* eb1 = (const float*)d_in[4];
    const float* ew2 = (const float*)d_in[5];
    const float* eb2 = (const float*)d_in[6];
    const float* nw1 = (const float*)d_in[7];
    const float* nb1 = (const float*)d_in[8];
    const float* nw2 = (const float*)d_in[9];
    const float* nb2 = (const float*)d_in[10];
    const float* chw = (const float*)d_in[11];
    const float* chb = (const float*)d_in[12];
    const float* cww = (const float*)d_in[13];
    const float* aw  = (const float*)d_in[14];
    const float* ab  = (const float*)d_in[15];

    float* ws    = (float*)d_ws;
    float* ha    = ws;             // 65536
    float* hb    = ws + 65536;     // 65536
    float* hn1   = ws + 131072;    // 65536
    float* agg   = ws + 196608;    // 65536
    float* delta = ws + 262144;    // 3072

    float* outh = (float*)d_out;       // 65536
    float* outx = outh + 65536;        // 3072

    precompute_kernel<<<768, 256, 0, stream>>>(h, ew1, eb1, nw1, nb1, ha, hb, hn1);
    edge_mfma_kernel<<<256, 512, 0, stream>>>(x, Lp, ha, hb, ew1, ew2, eb2, chw, chb,
                                              aw, ab, cww, agg, delta);
    node_fused_kernel<<<256, 256, 0, stream>>>(h, hn1, agg, nw1, nw2, nb2, x, delta,
                                               Lp, outh, outx);
}

// Round 8
// 144.693 us; speedup vs baseline: 2.0049x; 1.0698x over previous
//
#include <hip/hip_runtime.h>

#define Nn 1024

typedef __attribute__((ext_vector_type(8))) short short8v;
typedef __attribute__((ext_vector_type(4))) float floatx4;

// hardware-rate reciprocal / sqrt (v_rcp_f32 / v_sqrt_f32, ~1ulp).
// Plain '/' compiles to the ~10-instr IEEE div sequence — was dominant VALU cost.
__device__ __forceinline__ float frcp(float v)  { return __builtin_amdgcn_rcpf(v); }
__device__ __forceinline__ float fsilu(float v) { return v * frcp(1.0f + __expf(-v)); }
__device__ __forceinline__ float fsig(float v)  { return frcp(1.0f + __expf(-v)); }
__device__ __forceinline__ float ftanh10(float v){ return 10.0f - 20.0f * frcp(__expf(2.0f * v) + 1.0f); }

// pack two fp32 -> one u32 of 2 bf16 (round-half-up): 2 adds + 1 v_perm
__device__ __forceinline__ unsigned pkbf(float lo, float hi) {
    unsigned a = __float_as_uint(lo) + 0x8000u;
    unsigned b = __float_as_uint(hi) + 0x8000u;
    return __builtin_amdgcn_perm(b, a, 0x07060302u);  // {b.hi16, a.hi16}
}

// Kernel A: ha = h@Wa^T + eb1 ; hb = h@Wb^T ; hn1 = h@nw1[:, :64]^T + nb1
__global__ __launch_bounds__(256) void precompute_kernel(
    const float* __restrict__ h, const float* __restrict__ ew1,
    const float* __restrict__ eb1, const float* __restrict__ nw1,
    const float* __restrict__ nb1, float* __restrict__ ha,
    float* __restrict__ hb, float* __restrict__ hn1)
{
    int t = blockIdx.x * 256 + threadIdx.x;
    int which = t >> 16;
    int rem = t & 65535;
    int i = rem >> 6, o = rem & 63;
    const float* hrow = h + i * 64;
    const float* wrow;
    float acc;
    if (which == 0)      { wrow = ew1 + o * 130;      acc = eb1[o]; }
    else if (which == 1) { wrow = ew1 + o * 130 + 64; acc = 0.0f;   }
    else                 { wrow = nw1 + o * 128;      acc = nb1[o]; }
    #pragma unroll
    for (int k = 0; k < 64; ++k) acc = fmaf(hrow[k], wrow[k], acc);
    if (which == 0)      ha[rem]  = acc;
    else if (which == 1) hb[rem]  = acc;
    else                 hn1[rem] = acc;
}

// Edge pipeline. 1024 blocks x 256 thr (4 waves): block owns node i0 = blockIdx.x,
// wave w owns j-quarter [w*256, w*256+256) in 16 chunks of 16 edges.
// (R7 was grid=256: launch geometry capped occupancy at 1 block/CU = 25%.
//  hb is 256KB = L2-resident regardless of block scheduling, so lock-step
//  was unnecessary; 4 blocks/CU -> 16 waves/CU.)
// Chunk loop is wave-private (per-wave Tb slice): NO barriers inside.
// Both GEMMs computed swapped: D^T = W * T^T, output col = edge row = lane&15.
// waves_per_eu(2,4): min2 -> 256-reg budget (no forced spill), max4 -> 128-reg
// target; R7 landed 120 VGPR with identical body = 4 waves/SIMD.
__global__ __launch_bounds__(256) __attribute__((amdgpu_waves_per_eu(2, 4)))
void edge_mfma_kernel(
    const float* __restrict__ x, const float* __restrict__ Lp,
    const float* __restrict__ ha, const float* __restrict__ hb,
    const float* __restrict__ ew1, const float* __restrict__ ew2,
    const float* __restrict__ eb2, const float* __restrict__ chw,
    const float* __restrict__ chb, const float* __restrict__ aw,
    const float* __restrict__ ab, const float* __restrict__ cww,
    float* __restrict__ agg, float* __restrict__ delta)
{
    __shared__ __align__(16) char Tb[4][16 * 128];   // per-wave 16 rows x 64 bf16, XOR-swizzled
    __shared__ __align__(16) float xs[Nn * 3];
    __shared__ float dxs[4][3][16];
    __shared__ float redagg[4][64];
    __shared__ float sdel[4][3];

    const int tid  = threadIdx.x;
    const int wave = tid >> 6, lane = tid & 63;
    const int lr = lane & 15, g = lane >> 4;
    const int i0 = blockIdx.x;
    const int jbase = wave * 256;
    const int rsub = lane >> 5;          // build: which of 2 rows
    const int kp   = (lane & 31) * 2;    // build: k-pair base (bf16 elements)
    const int ghi  = g >> 1;
    const int selA = (lr + ((g & 1) << 5)) << 2;   // bpermute byte addr
    const int selB = selA + 64;
    char* TbW = Tb[wave];

    // stage x into LDS (float4)
    {
        const float4* xsrc = (const float4*)x;
        float4* xdst = (float4*)xs;
        xdst[tid] = xsrc[tid];
        xdst[tid + 256] = xsrc[tid + 256];
        xdst[tid + 512] = xsrc[tid + 512];
    }

    // weight fragments in registers (bf16): row n = lane&15, k 8-contig per g
    short8v bw2[2][4], bwc[2][4];
    #pragma unroll
    for (int kt = 0; kt < 2; ++kt)
      #pragma unroll
      for (int nt = 0; nt < 4; ++nt) {
        int n = nt * 16 + lr;
        int k0 = kt * 32 + g * 8;
        float4 lo = *(const float4*)(ew2 + n * 64 + k0);
        float4 hi = *(const float4*)(ew2 + n * 64 + k0 + 4);
        union { short8v s; unsigned u[4]; } pk;
        pk.u[0] = pkbf(lo.x, lo.y); pk.u[1] = pkbf(lo.z, lo.w);
        pk.u[2] = pkbf(hi.x, hi.y); pk.u[3] = pkbf(hi.z, hi.w);
        bw2[kt][nt] = pk.s;
        lo = *(const float4*)(chw + n * 64 + k0);
        hi = *(const float4*)(chw + n * 64 + k0 + 4);
        pk.u[0] = pkbf(lo.x, lo.y); pk.u[1] = pkbf(lo.z, lo.w);
        pk.u[2] = pkbf(hi.x, hi.y); pk.u[3] = pkbf(hi.z, hi.w);
        bwc[kt][nt] = pk.s;
      }

    // per-lane bias/weight vectors, in registers (n = nt*16 + g*4 + r)
    floatx4 ebr[4], awr[4], chbr[4], cwr[4];
    #pragma unroll
    for (int nt = 0; nt < 4; ++nt) {
      int n4 = nt * 16 + (g << 2);
      ebr[nt]  = *(const floatx4*)(eb2 + n4);
      awr[nt]  = *(const floatx4*)(aw  + n4);
      chbr[nt] = *(const floatx4*)(chb + n4);
      cwr[nt]  = *(const floatx4*)(cww + n4);
    }

    const float L = Lp[0], invL = frcp(L);
    const float ab0 = ab[0];
    const float2 hv = *(const float2*)(ha + i0 * 64 + kp);
    const float hav0 = hv.x, hav1 = hv.y;
    const float2 w1a = *(const float2*)(ew1 + kp * 130 + 128);
    const float2 w1b = *(const float2*)(ew1 + (kp + 1) * 130 + 128);
    const float wr0 = w1a.x + w1a.y, wr1 = w1b.x + w1b.y;

    floatx4 agg4[4];
    #pragma unroll
    for (int nt = 0; nt < 4; ++nt) agg4[nt] = (floatx4){0.f, 0.f, 0.f, 0.f};
    float dp0 = 0.f, dp1 = 0.f, dp2 = 0.f;

    __syncthreads();

    const float xi0 = xs[i0 * 3 + 0], xi1 = xs[i0 * 3 + 1], xi2 = xs[i0 * 3 + 2];

    for (int jc = 0; jc < 16; ++jc) {
      // ---- build T = silu(ha + hb + radial*wr) for this wave's 16 rows ----
      #pragma unroll
      for (int it = 0; it < 8; ++it) {
        const int row = it * 2 + rsub;
        const int j = jbase + jc * 16 + row;
        float xd0 = xi0 - xs[j * 3 + 0];
        float xd1 = xi1 - xs[j * 3 + 1];
        float xd2 = xi2 - xs[j * 3 + 2];
        float d0 = xd0 - L * floorf(fmaf(xd0, invL, 0.5f));
        float d1 = xd1 - L * floorf(fmaf(xd1, invL, 0.5f));
        float d2 = xd2 - L * floorf(fmaf(xd2, invL, 0.5f));
        float radial = d0 * d0 + d1 * d1 + d2 * d2;
        float cinv = frcp(__builtin_amdgcn_sqrtf(radial + 1e-8f) + 1.0f);
        float2 hbv = *(const float2*)(hb + j * 64 + kp);
        float plo = fmaf(radial, wr0, hav0) + hbv.x;
        float phi = fmaf(radial, wr1, hav1) + hbv.y;
        unsigned pu = pkbf(fsilu(plo), fsilu(phi));
        // 16B unit holds 8 bf16: unit = kp>>3 (0..7), pair slot = (kp>>1)&3
        int unit = (kp >> 3) ^ (row & 7);
        *(unsigned*)(TbW + row * 128 + unit * 16 + (((kp >> 1) & 3) << 2)) = pu;
        if ((lane & 31) == 0) {
          dxs[wave][0][row] = d0 * cinv;
          dxs[wave][1][row] = d1 * cinv;
          dxs[wave][2][row] = d2 * cinv;
        }
      }
      // no barrier: Tb slice is wave-private

      // ---- GEMM1 (swapped): D1^T = ew2 * T^T ; C-init = eb2 ----
      short8v tf[2];
      #pragma unroll
      for (int kt = 0; kt < 2; ++kt) {
        int unit = (kt * 4 + g) ^ (lr & 7);
        tf[kt] = *(const short8v*)(TbW + lr * 128 + unit * 16);
      }
      floatx4 acc[4];
      #pragma unroll
      for (int nt = 0; nt < 4; ++nt) acc[nt] = ebr[nt];
      #pragma unroll
      for (int kt = 0; kt < 2; ++kt)
        #pragma unroll
        for (int nt = 0; nt < 4; ++nt)
          acc[nt] = __builtin_amdgcn_mfma_f32_16x16x32_bf16(bw2[kt][nt], tf[kt], acc[nt], 0, 0, 0);

      // ---- epilogue 1: silu, att (row-dot over n), e, agg ----
      float p = 0.f;
      #pragma unroll
      for (int nt = 0; nt < 4; ++nt)
        #pragma unroll
        for (int r = 0; r < 4; ++r) {
          float s = fsilu(acc[nt][r]);
          acc[nt][r] = s;
          p = fmaf(s, awr[nt][r], p);
        }
      p += __shfl_xor(p, 16); p += __shfl_xor(p, 32);
      const float att = fsig(p + ab0);

      unsigned Pq[4][2];
      #pragma unroll
      for (int nt = 0; nt < 4; ++nt) {
        float e0 = acc[nt][0] * att, e1 = acc[nt][1] * att;
        float e2 = acc[nt][2] * att, e3 = acc[nt][3] * att;
        agg4[nt][0] += e0; agg4[nt][1] += e1;
        agg4[nt][2] += e2; agg4[nt][3] += e3;
        Pq[nt][0] = pkbf(e0, e1);
        Pq[nt][1] = pkbf(e2, e3);
      }

      // ---- assemble GEMM2 B-frags (E^T) in-register via bpermute ----
      union { short8v s; int u[4]; } ef[2];
      #pragma unroll
      for (int kt2 = 0; kt2 < 2; ++kt2)
        #pragma unroll
        for (int w = 0; w < 4; ++w) {
          int sel = (w < 2) ? selA : selB;
          int v0 = __builtin_amdgcn_ds_bpermute(sel, (int)Pq[kt2 * 2][w & 1]);
          int v1 = __builtin_amdgcn_ds_bpermute(sel, (int)Pq[kt2 * 2 + 1][w & 1]);
          ef[kt2].u[w] = ghi ? v1 : v0;
        }

      // ---- GEMM2 (swapped): D2^T = chw * E^T ; C-init = chb ----
      floatx4 acc2[4];
      #pragma unroll
      for (int nt = 0; nt < 4; ++nt) acc2[nt] = chbr[nt];
      #pragma unroll
      for (int kt2 = 0; kt2 < 2; ++kt2)
        #pragma unroll
        for (int nt = 0; nt < 4; ++nt)
          acc2[nt] = __builtin_amdgcn_mfma_f32_16x16x32_bf16(bwc[kt2][nt], ef[kt2].s, acc2[nt], 0, 0, 0);

      // ---- epilogue 2: silu, cww-dot, tanh, delta ----
      float q = 0.f;
      #pragma unroll
      for (int nt = 0; nt < 4; ++nt)
        #pragma unroll
        for (int r = 0; r < 4; ++r)
          q = fmaf(fsilu(acc2[nt][r]), cwr[nt][r], q);
      q += __shfl_xor(q, 16); q += __shfl_xor(q, 32);
      const float wvv = ftanh10(q);
      if (g == 0) {
        dp0 = fmaf(dxs[wave][0][lr], wvv, dp0);
        dp1 = fmaf(dxs[wave][1][lr], wvv, dp1);
        dp2 = fmaf(dxs[wave][2][lr], wvv, dp2);
      }
    }

    // ---- final reductions: reduce over edge rows (lr) within wave ----
    #pragma unroll
    for (int nt = 0; nt < 4; ++nt)
      #pragma unroll
      for (int r = 0; r < 4; ++r) {
        float v = agg4[nt][r];
        v += __shfl_xor(v, 1); v += __shfl_xor(v, 2);
        v += __shfl_xor(v, 4); v += __shfl_xor(v, 8);
        agg4[nt][r] = v;
      }
    if (lr == 0) {
      #pragma unroll
      for (int nt = 0; nt < 4; ++nt)
        *(floatx4*)&redagg[wave][nt * 16 + (g << 2)] = agg4[nt];
    }
    dp0 += __shfl_xor(dp0, 1); dp0 += __shfl_xor(dp0, 2); dp0 += __shfl_xor(dp0, 4); dp0 += __shfl_xor(dp0, 8);
    dp1 += __shfl_xor(dp1, 1); dp1 += __shfl_xor(dp1, 2); dp1 += __shfl_xor(dp1, 4); dp1 += __shfl_xor(dp1, 8);
    dp2 += __shfl_xor(dp2, 1); dp2 += __shfl_xor(dp2, 2); dp2 += __shfl_xor(dp2, 4); dp2 += __shfl_xor(dp2, 8);
    if (lane == 0) { sdel[wave][0] = dp0; sdel[wave][1] = dp1; sdel[wave][2] = dp2; }
    __syncthreads();
    if (tid < 64)
      agg[i0 * 64 + tid] = redagg[0][tid] + redagg[1][tid] + redagg[2][tid] + redagg[3][tid];
    else if (tid < 67) {
      int d = tid - 64;
      delta[i0 * 3 + d] = sdel[0][d] + sdel[1][d] + sdel[2][d] + sdel[3][d];
    }
}

// Fused node update + x_new. 256 blocks x 256 thr; block owns 4 nodes.
__global__ __launch_bounds__(256) void node_fused_kernel(
    const float* __restrict__ h, const float* __restrict__ hn1,
    const float* __restrict__ agg, const float* __restrict__ nw1,
    const float* __restrict__ nw2, const float* __restrict__ nb2,
    const float* __restrict__ x, const float* __restrict__ delta,
    const float* __restrict__ Lp, float* __restrict__ outh,
    float* __restrict__ outx)
{
    __shared__ float sps[256];
    const int b = blockIdx.x, tid = threadIdx.x;
    const int gt = b * 256 + tid;
    const int i = gt >> 6, o = gt & 63;
    const float* arow = agg + i * 64;
    const float* wrow = nw1 + o * 128 + 64;
    float acc = hn1[gt];
    #pragma unroll
    for (int k = 0; k < 64; ++k) acc = fmaf(arow[k], wrow[k], acc);
    sps[tid] = fsilu(acc);
    __syncthreads();
    const float* srow = sps + (tid & ~63);
    const float* w2row = nw2 + o * 64;
    float acc2 = h[gt] + nb2[o];
    #pragma unroll
    for (int k = 0; k < 64; ++k) acc2 = fmaf(srow[k], w2row[k], acc2);
    outh[gt] = acc2;
    if (tid < 12) {
        int ii = b * 4 + tid / 3, d = tid % 3;
        float L = Lp[0];
        float v = x[ii * 3 + d] + delta[ii * 3 + d];
        outx[ii * 3 + d] = v - L * floorf(v * frcp(L));
    }
}

extern "C" void kernel_launch(void* const* d_in, const int* in_sizes, int n_in,
                              void* d_out, int out_size, void* d_ws, size_t ws_size,
                              hipStream_t stream) {
    const float* h   = (const float*)d_in[0];
    const float* x   = (const float*)d_in[1];
    const float* Lp  = (const float*)d_in[2];
    const float* ew1 = (const float*)d_in[3];
    const float* eb1 = (const float*)d_in[4];
    const float* ew2 = (const float*)d_in[5];
    const float* eb2 = (const float*)d_in[6];
    const float* nw1 = (const float*)d_in[7];
    const float* nb1 = (const float*)d_in[8];
    const float* nw2 = (const float*)d_in[9];
    const float* nb2 = (const float*)d_in[10];
    const float* chw = (const float*)d_in[11];
    const float* chb = (const float*)d_in[12];
    const float* cww = (const float*)d_in[13];
    const float* aw  = (const float*)d_in[14];
    const float* ab  = (const float*)d_in[15];

    float* ws    = (float*)d_ws;
    float* ha    = ws;             // 65536
    float* hb    = ws + 65536;     // 65536
    float* hn1   = ws + 131072;    // 65536
    float* agg   = ws + 196608;    // 65536
    float* delta = ws + 262144;    // 3072

    float* outh = (float*)d_out;       // 65536
    float* outx = outh + 65536;        // 3072

    precompute_kernel<<<768, 256, 0, stream>>>(h, ew1, eb1, nw1, nb1, ha, hb, hn1);
    edge_mfma_kernel<<<1024, 256, 0, stream>>>(x, Lp, ha, hb, ew1, ew2, eb2, chw, chb,
                                               aw, ab, cww, agg, delta);
    node_fused_kernel<<<256, 256, 0, stream>>>(h, hn1, agg, nw1, nw2, nb2, x, delta,
                                               Lp, outh, outx);
}

// Round 9
// 138.334 us; speedup vs baseline: 2.0971x; 1.0460x over previous
//
#include <hip/hip_runtime.h>

#define Nn 1024

typedef __attribute__((ext_vector_type(8))) short short8v;
typedef __attribute__((ext_vector_type(4))) float floatx4;

// hardware-rate reciprocal / sqrt (v_rcp_f32 / v_sqrt_f32, ~1ulp).
__device__ __forceinline__ float frcp(float v)  { return __builtin_amdgcn_rcpf(v); }
__device__ __forceinline__ float fsilu(float v) { return v * frcp(1.0f + __expf(-v)); }
__device__ __forceinline__ float fsig(float v)  { return frcp(1.0f + __expf(-v)); }
__device__ __forceinline__ float ftanh10(float v){ return 10.0f - 20.0f * frcp(__expf(2.0f * v) + 1.0f); }

// pack two fp32 -> one u32 of 2 bf16 (round-half-up): 2 adds + 1 v_perm
__device__ __forceinline__ unsigned pkbf(float lo, float hi) {
    unsigned a = __float_as_uint(lo) + 0x8000u;
    unsigned b = __float_as_uint(hi) + 0x8000u;
    return __builtin_amdgcn_perm(b, a, 0x07060302u);  // {b.hi16, a.hi16}
}

union I4S8 { int4 i; short8v s; };

// Kernel A: ha = h@Wa^T + eb1 ; hb = h@Wb^T ; hn1 = h@nw1[:, :64]^T + nb1
__global__ __launch_bounds__(256) void precompute_kernel(
    const float* __restrict__ h, const float* __restrict__ ew1,
    const float* __restrict__ eb1, const float* __restrict__ nw1,
    const float* __restrict__ nb1, float* __restrict__ ha,
    float* __restrict__ hb, float* __restrict__ hn1)
{
    int t = blockIdx.x * 256 + threadIdx.x;
    int which = t >> 16;
    int rem = t & 65535;
    int i = rem >> 6, o = rem & 63;
    const float* hrow = h + i * 64;
    const float* wrow;
    float acc;
    if (which == 0)      { wrow = ew1 + o * 130;      acc = eb1[o]; }
    else if (which == 1) { wrow = ew1 + o * 130 + 64; acc = 0.0f;   }
    else                 { wrow = nw1 + o * 128;      acc = nb1[o]; }
    #pragma unroll
    for (int k = 0; k < 64; ++k) acc = fmaf(hrow[k], wrow[k], acc);
    if (which == 0)      ha[rem]  = acc;
    else if (which == 1) hb[rem]  = acc;
    else                 hn1[rem] = acc;
}

// Edge pipeline. 1024 blocks x 256 thr (4 waves): block owns node i0 = blockIdx.x,
// wave w owns j-quarter in 16 chunks of 16 edges. Chunk loop is wave-private.
// Both GEMMs computed swapped: D^T = W * T^T, output col = edge row = lane&15.
// R9: weight fragments live in LDS (read per-MFMA, laundered index defeats LICM)
// to cut ~64 regs of unified VGPR/AGPR footprint (R7/R8 were stuck at
// 2 waves/SIMD because arch+acc ~190 regs); geometry computed once per edge
// (16-lane pre-pass) instead of 32x-redundantly.
__global__ __launch_bounds__(256) __attribute__((amdgpu_waves_per_eu(3, 4)))
void edge_mfma_kernel(
    const float* __restrict__ x, const float* __restrict__ Lp,
    const float* __restrict__ ha, const float* __restrict__ hb,
    const float* __restrict__ ew1, const float* __restrict__ ew2,
    const float* __restrict__ eb2, const float* __restrict__ chw,
    const float* __restrict__ chb, const float* __restrict__ aw,
    const float* __restrict__ ab, const float* __restrict__ cww,
    float* __restrict__ agg, float* __restrict__ delta)
{
    __shared__ __align__(16) int4 Wlds[2][2][4][64];   // [w2|wc][kt][nt][lane] packed bf16 frags, 16KB
    __shared__ __align__(16) char Tb[4][16 * 128];     // per-wave 16 rows x 64 bf16, XOR-swizzled
    __shared__ __align__(16) float xs[Nn * 3];
    __shared__ float rad_lds[4][16];
    __shared__ float dxs[4][3][16];
    __shared__ float redagg[4][64];
    __shared__ float sdel[4][3];

    const int tid  = threadIdx.x;
    const int wave = tid >> 6, lane = tid & 63;
    const int lr = lane & 15, g = lane >> 4;
    const int i0 = blockIdx.x;
    const int jbase = wave * 256;
    const int rsub = lane >> 5;          // build: which of 2 rows
    const int kp   = (lane & 31) * 2;    // build: k-pair base (bf16 elements)
    const int ghi  = g >> 1;
    const int selA = (lr + ((g & 1) << 5)) << 2;   // bpermute byte addr
    const int selB = selA + 64;
    char* TbW = Tb[wave];
    const int4* WldsF = &Wlds[0][0][0][0];

    // stage x into LDS (float4)
    {
        const float4* xsrc = (const float4*)x;
        float4* xdst = (float4*)xs;
        xdst[tid] = xsrc[tid];
        xdst[tid + 256] = xsrc[tid + 256];
        xdst[tid + 512] = xsrc[tid + 512];
    }

    // wave 0 stages packed weight fragments into LDS (per-lane frag identical
    // across waves): row n = lane&15, k 8-contig per g.
    if (wave == 0) {
      #pragma unroll
      for (int kt = 0; kt < 2; ++kt)
        #pragma unroll
        for (int nt = 0; nt < 4; ++nt) {
          int n = nt * 16 + lr;
          int k0 = kt * 32 + g * 8;
          float4 lo = *(const float4*)(ew2 + n * 64 + k0);
          float4 hi = *(const float4*)(ew2 + n * 64 + k0 + 4);
          Wlds[0][kt][nt][lane] = make_int4(
              (int)pkbf(lo.x, lo.y), (int)pkbf(lo.z, lo.w),
              (int)pkbf(hi.x, hi.y), (int)pkbf(hi.z, hi.w));
          lo = *(const float4*)(chw + n * 64 + k0);
          hi = *(const float4*)(chw + n * 64 + k0 + 4);
          Wlds[1][kt][nt][lane] = make_int4(
              (int)pkbf(lo.x, lo.y), (int)pkbf(lo.z, lo.w),
              (int)pkbf(hi.x, hi.y), (int)pkbf(hi.z, hi.w));
        }
    }

    // per-lane bias/weight vectors, in registers (n = nt*16 + g*4 + r)
    floatx4 ebr[4], awr[4], chbr[4], cwr[4];
    #pragma unroll
    for (int nt = 0; nt < 4; ++nt) {
      int n4 = nt * 16 + (g << 2);
      ebr[nt]  = *(const floatx4*)(eb2 + n4);
      awr[nt]  = *(const floatx4*)(aw  + n4);
      chbr[nt] = *(const floatx4*)(chb + n4);
      cwr[nt]  = *(const floatx4*)(cww + n4);
    }

    const float L = Lp[0], invL = frcp(L);
    const float ab0 = ab[0];
    const float2 hv = *(const float2*)(ha + i0 * 64 + kp);
    const float hav0 = hv.x, hav1 = hv.y;
    const float2 w1a = *(const float2*)(ew1 + kp * 130 + 128);
    const float2 w1b = *(const float2*)(ew1 + (kp + 1) * 130 + 128);
    const float wr0 = w1a.x + w1a.y, wr1 = w1b.x + w1b.y;

    floatx4 agg4[4];
    #pragma unroll
    for (int nt = 0; nt < 4; ++nt) agg4[nt] = (floatx4){0.f, 0.f, 0.f, 0.f};
    float dp0 = 0.f, dp1 = 0.f, dp2 = 0.f;

    __syncthreads();

    const float xi0 = xs[i0 * 3 + 0], xi1 = xs[i0 * 3 + 1], xi2 = xs[i0 * 3 + 2];

    for (int jc = 0; jc < 16; ++jc) {
      // laundered lane index: makes the per-chunk weight ds_reads opaque to
      // LICM so they are NOT hoisted into 64 live registers.
      unsigned lidx = (unsigned)lane;
      asm volatile("" : "+v"(lidx));

      // ---- geometry pre-pass: one lane per edge (16 lanes) ----
      if (lane < 16) {
        const int j = jbase + jc * 16 + lane;
        float xd0 = xi0 - xs[j * 3 + 0];
        float xd1 = xi1 - xs[j * 3 + 1];
        float xd2 = xi2 - xs[j * 3 + 2];
        float d0 = xd0 - L * floorf(fmaf(xd0, invL, 0.5f));
        float d1 = xd1 - L * floorf(fmaf(xd1, invL, 0.5f));
        float d2 = xd2 - L * floorf(fmaf(xd2, invL, 0.5f));
        float radial = d0 * d0 + d1 * d1 + d2 * d2;
        float cinv = frcp(__builtin_amdgcn_sqrtf(radial + 1e-8f) + 1.0f);
        rad_lds[wave][lane] = radial;
        dxs[wave][0][lane] = d0 * cinv;
        dxs[wave][1][lane] = d1 * cinv;
        dxs[wave][2][lane] = d2 * cinv;
      }
      // no barrier: wave-private; compiler inserts lgkmcnt before reads

      // ---- build T = silu(ha + hb + radial*wr) for this wave's 16 rows ----
      #pragma unroll
      for (int it = 0; it < 8; ++it) {
        const int row = it * 2 + rsub;
        const int j = jbase + jc * 16 + row;
        float radial = rad_lds[wave][row];                 // LDS broadcast
        float2 hbv = *(const float2*)(hb + j * 64 + kp);
        float plo = fmaf(radial, wr0, hav0) + hbv.x;
        float phi = fmaf(radial, wr1, hav1) + hbv.y;
        unsigned pu = pkbf(fsilu(plo), fsilu(phi));
        // 16B unit holds 8 bf16: unit = kp>>3 (0..7), pair slot = (kp>>1)&3
        int unit = (kp >> 3) ^ (row & 7);
        *(unsigned*)(TbW + row * 128 + unit * 16 + (((kp >> 1) & 3) << 2)) = pu;
      }

      // ---- GEMM1 (swapped): D1^T = ew2 * T^T ; C-init = eb2 ----
      short8v tf[2];
      #pragma unroll
      for (int kt = 0; kt < 2; ++kt) {
        int unit = (kt * 4 + g) ^ (lr & 7);
        tf[kt] = *(const short8v*)(TbW + lr * 128 + unit * 16);
      }
      floatx4 acc[4];
      #pragma unroll
      for (int nt = 0; nt < 4; ++nt) acc[nt] = ebr[nt];
      #pragma unroll
      for (int kt = 0; kt < 2; ++kt)
        #pragma unroll
        for (int nt = 0; nt < 4; ++nt) {
          I4S8 wv; wv.i = WldsF[(kt * 4 + nt) * 64 + lidx];
          acc[nt] = __builtin_amdgcn_mfma_f32_16x16x32_bf16(wv.s, tf[kt], acc[nt], 0, 0, 0);
        }

      // ---- epilogue 1: silu, att (row-dot over n), e, agg ----
      float p = 0.f;
      #pragma unroll
      for (int nt = 0; nt < 4; ++nt)
        #pragma unroll
        for (int r = 0; r < 4; ++r) {
          float s = fsilu(acc[nt][r]);
          acc[nt][r] = s;
          p = fmaf(s, awr[nt][r], p);
        }
      p += __shfl_xor(p, 16); p += __shfl_xor(p, 32);
      const float att = fsig(p + ab0);

      unsigned Pq[4][2];
      #pragma unroll
      for (int nt = 0; nt < 4; ++nt) {
        float e0 = acc[nt][0] * att, e1 = acc[nt][1] * att;
        float e2 = acc[nt][2] * att, e3 = acc[nt][3] * att;
        agg4[nt][0] += e0; agg4[nt][1] += e1;
        agg4[nt][2] += e2; agg4[nt][3] += e3;
        Pq[nt][0] = pkbf(e0, e1);
        Pq[nt][1] = pkbf(e2, e3);
      }

      // ---- assemble GEMM2 B-frags (E^T) in-register via bpermute ----
      union { short8v s; int u[4]; } ef[2];
      #pragma unroll
      for (int kt2 = 0; kt2 < 2; ++kt2)
        #pragma unroll
        for (int w = 0; w < 4; ++w) {
          int sel = (w < 2) ? selA : selB;
          int v0 = __builtin_amdgcn_ds_bpermute(sel, (int)Pq[kt2 * 2][w & 1]);
          int v1 = __builtin_amdgcn_ds_bpermute(sel, (int)Pq[kt2 * 2 + 1][w & 1]);
          ef[kt2].u[w] = ghi ? v1 : v0;
        }

      // ---- GEMM2 (swapped): D2^T = chw * E^T ; C-init = chb ----
      floatx4 acc2[4];
      #pragma unroll
      for (int nt = 0; nt < 4; ++nt) acc2[nt] = chbr[nt];
      #pragma unroll
      for (int kt2 = 0; kt2 < 2; ++kt2)
        #pragma unroll
        for (int nt = 0; nt < 4; ++nt) {
          I4S8 wv; wv.i = WldsF[512 + (kt2 * 4 + nt) * 64 + lidx];
          acc2[nt] = __builtin_amdgcn_mfma_f32_16x16x32_bf16(wv.s, ef[kt2].s, acc2[nt], 0, 0, 0);
        }

      // ---- epilogue 2: silu, cww-dot, tanh, delta ----
      float q = 0.f;
      #pragma unroll
      for (int nt = 0; nt < 4; ++nt)
        #pragma unroll
        for (int r = 0; r < 4; ++r)
          q = fmaf(fsilu(acc2[nt][r]), cwr[nt][r], q);
      q += __shfl_xor(q, 16); q += __shfl_xor(q, 32);
      const float wvv = ftanh10(q);
      if (g == 0) {
        dp0 = fmaf(dxs[wave][0][lr], wvv, dp0);
        dp1 = fmaf(dxs[wave][1][lr], wvv, dp1);
        dp2 = fmaf(dxs[wave][2][lr], wvv, dp2);
      }
    }

    // ---- final reductions: reduce over edge rows (lr) within wave ----
    #pragma unroll
    for (int nt = 0; nt < 4; ++nt)
      #pragma unroll
      for (int r = 0; r < 4; ++r) {
        float v = agg4[nt][r];
        v += __shfl_xor(v, 1); v += __shfl_xor(v, 2);
        v += __shfl_xor(v, 4); v += __shfl_xor(v, 8);
        agg4[nt][r] = v;
      }
    if (lr == 0) {
      #pragma unroll
      for (int nt = 0; nt < 4; ++nt)
        *(floatx4*)&redagg[wave][nt * 16 + (g << 2)] = agg4[nt];
    }
    dp0 += __shfl_xor(dp0, 1); dp0 += __shfl_xor(dp0, 2); dp0 += __shfl_xor(dp0, 4); dp0 += __shfl_xor(dp0, 8);
    dp1 += __shfl_xor(dp1, 1); dp1 += __shfl_xor(dp1, 2); dp1 += __shfl_xor(dp1, 4); dp1 += __shfl_xor(dp1, 8);
    dp2 += __shfl_xor(dp2, 1); dp2 += __shfl_xor(dp2, 2); dp2 += __shfl_xor(dp2, 4); dp2 += __shfl_xor(dp2, 8);
    if (lane == 0) { sdel[wave][0] = dp0; sdel[wave][1] = dp1; sdel[wave][2] = dp2; }
    __syncthreads();
    if (tid < 64)
      agg[i0 * 64 + tid] = redagg[0][tid] + redagg[1][tid] + redagg[2][tid] + redagg[3][tid];
    else if (tid < 67) {
      int d = tid - 64;
      delta[i0 * 3 + d] = sdel[0][d] + sdel[1][d] + sdel[2][d] + sdel[3][d];
    }
}

// Fused node update + x_new. 256 blocks x 256 thr; block owns 4 nodes.
__global__ __launch_bounds__(256) void node_fused_kernel(
    const float* __restrict__ h, const float* __restrict__ hn1,
    const float* __restrict__ agg, const float* __restrict__ nw1,
    const float* __restrict__ nw2, const float* __restrict__ nb2,
    const float* __restrict__ x, const float* __restrict__ delta,
    const float* __restrict__ Lp, float* __restrict__ outh,
    float* __restrict__ outx)
{
    __shared__ float sps[256];
    const int b = blockIdx.x, tid = threadIdx.x;
    const int gt = b * 256 + tid;
    const int i = gt >> 6, o = gt & 63;
    const float* arow = agg + i * 64;
    const float* wrow = nw1 + o * 128 + 64;
    float acc = hn1[gt];
    #pragma unroll
    for (int k = 0; k < 64; ++k) acc = fmaf(arow[k], wrow[k], acc);
    sps[tid] = fsilu(acc);
    __syncthreads();
    const float* srow = sps + (tid & ~63);
    const float* w2row = nw2 + o * 64;
    float acc2 = h[gt] + nb2[o];
    #pragma unroll
    for (int k = 0; k < 64; ++k) acc2 = fmaf(srow[k], w2row[k], acc2);
    outh[gt] = acc2;
    if (tid < 12) {
        int ii = b * 4 + tid / 3, d = tid % 3;
        float L = Lp[0];
        float v = x[ii * 3 + d] + delta[ii * 3 + d];
        outx[ii * 3 + d] = v - L * floorf(v * frcp(L));
    }
}

extern "C" void kernel_launch(void* const* d_in, const int* in_sizes, int n_in,
                              void* d_out, int out_size, void* d_ws, size_t ws_size,
                              hipStream_t stream) {
    const float* h   = (const float*)d_in[0];
    const float* x   = (const float*)d_in[1];
    const float* Lp  = (const float*)d_in[2];
    const float* ew1 = (const float*)d_in[3];
    const float* eb1 = (const float*)d_in[4];
    const float* ew2 = (const float*)d_in[5];
    const float* eb2 = (const float*)d_in[6];
    const float* nw1 = (const float*)d_in[7];
    const float* nb1 = (const float*)d_in[8];
    const float* nw2 = (const float*)d_in[9];
    const float* nb2 = (const float*)d_in[10];
    const float* chw = (const float*)d_in[11];
    const float* chb = (const float*)d_in[12];
    const float* cww = (const float*)d_in[13];
    const float* aw  = (const float*)d_in[14];
    const float* ab  = (const float*)d_in[15];

    float* ws    = (float*)d_ws;
    float* ha    = ws;             // 65536
    float* hb    = ws + 65536;     // 65536
    float* hn1   = ws + 131072;    // 65536
    float* agg   = ws + 196608;    // 65536
    float* delta = ws + 262144;    // 3072

    float* outh = (float*)d_out;       // 65536
    float* outx = outh + 65536;        // 3072

    precompute_kernel<<<768, 256, 0, stream>>>(h, ew1, eb1, nw1, nb1, ha, hb, hn1);
    edge_mfma_kernel<<<1024, 256, 0, stream>>>(x, Lp, ha, hb, ew1, ew2, eb2, chw, chb,
                                               aw, ab, cww, agg, delta);
    node_fused_kernel<<<256, 256, 0, stream>>>(h, hn1, agg, nw1, nw2, nb2, x, delta,
                                               Lp, outh, outx);
}

// Round 10
// 95.149 us; speedup vs baseline: 3.0489x; 1.4539x over previous
//
#include <hip/hip_runtime.h>

#define Nn 1024

typedef __attribute__((ext_vector_type(8))) short short8v;
typedef __attribute__((ext_vector_type(4))) float floatx4;

// hardware-rate reciprocal / sqrt (v_rcp_f32 / v_sqrt_f32, ~1ulp).
__device__ __forceinline__ float frcp(float v)  { return __builtin_amdgcn_rcpf(v); }
__device__ __forceinline__ float fsilu(float v) { return v * frcp(1.0f + __expf(-v)); }
__device__ __forceinline__ float fsig(float v)  { return frcp(1.0f + __expf(-v)); }
__device__ __forceinline__ float ftanh10(float v){ return 10.0f - 20.0f * frcp(__expf(2.0f * v) + 1.0f); }

// pack two fp32 -> one u32 of 2 bf16 (round-half-up): 2 adds + 1 v_perm
__device__ __forceinline__ unsigned pkbf(float lo, float hi) {
    unsigned a = __float_as_uint(lo) + 0x8000u;
    unsigned b = __float_as_uint(hi) + 0x8000u;
    return __builtin_amdgcn_perm(b, a, 0x07060302u);  // {b.hi16, a.hi16}
}

union I4S8 { int4 i; short8v s; };

// Kernel A: ha = h@Wa^T + eb1 ; hb = h@Wb^T ; hn1 = h@nw1[:, :64]^T + nb1
__global__ __launch_bounds__(256) void precompute_kernel(
    const float* __restrict__ h, const float* __restrict__ ew1,
    const float* __restrict__ eb1, const float* __restrict__ nw1,
    const float* __restrict__ nb1, float* __restrict__ ha,
    float* __restrict__ hb, float* __restrict__ hn1)
{
    int t = blockIdx.x * 256 + threadIdx.x;
    int which = t >> 16;
    int rem = t & 65535;
    int i = rem >> 6, o = rem & 63;
    const float* hrow = h + i * 64;
    const float* wrow;
    float acc;
    if (which == 0)      { wrow = ew1 + o * 130;      acc = eb1[o]; }
    else if (which == 1) { wrow = ew1 + o * 130 + 64; acc = 0.0f;   }
    else                 { wrow = nw1 + o * 128;      acc = nb1[o]; }
    #pragma unroll
    for (int k = 0; k < 64; ++k) acc = fmaf(hrow[k], wrow[k], acc);
    if (which == 0)      ha[rem]  = acc;
    else if (which == 1) hb[rem]  = acc;
    else                 hn1[rem] = acc;
}

// Edge pipeline. 1024 blocks x 256 thr (4 waves): block owns node i0 = blockIdx.x,
// wave w owns j-quarter in 16 chunks of 16 edges. Chunk loop is wave-private.
// Both GEMMs computed swapped: D^T = W * T^T, output col = edge row = lane&15.
// R10: T built DIRECTLY in B-fragment layout in registers (lane (lr,g) owns edge
// lr, channels kt*32+g*8..+8) — no Tb LDS round trip (R6's idea; safe now that
// weights live in LDS). hb loads for chunk jc+1 issued at top of chunk jc so
// L2 latency (~200cyc) hides under the chunk's compute.
__global__ __launch_bounds__(256) __attribute__((amdgpu_waves_per_eu(2, 3)))
void edge_mfma_kernel(
    const float* __restrict__ x, const float* __restrict__ Lp,
    const float* __restrict__ ha, const float* __restrict__ hb,
    const float* __restrict__ ew1, const float* __restrict__ ew2,
    const float* __restrict__ eb2, const float* __restrict__ chw,
    const float* __restrict__ chb, const float* __restrict__ aw,
    const float* __restrict__ ab, const float* __restrict__ cww,
    float* __restrict__ agg, float* __restrict__ delta)
{
    __shared__ __align__(16) int4 Wlds[2][2][4][64];   // [w2|wc][kt][nt][lane] packed bf16 frags, 16KB
    __shared__ __align__(16) float xs[Nn * 3];
    __shared__ float redagg[4][64];
    __shared__ float sdel[4][3];

    const int tid  = threadIdx.x;
    const int wave = tid >> 6, lane = tid & 63;
    const int lr = lane & 15, g = lane >> 4;
    const int i0 = blockIdx.x;
    const int jbase = wave * 256;
    const int ghi  = g >> 1;
    const int selA = (lr + ((g & 1) << 5)) << 2;   // bpermute byte addr
    const int selB = selA + 64;
    const int4* WldsF = &Wlds[0][0][0][0];

    // stage x into LDS (float4)
    {
        const float4* xsrc = (const float4*)x;
        float4* xdst = (float4*)xs;
        xdst[tid] = xsrc[tid];
        xdst[tid + 256] = xsrc[tid + 256];
        xdst[tid + 512] = xsrc[tid + 512];
    }

    // wave 0 stages packed weight fragments into LDS: row n = lane&15, k 8-contig per g.
    if (wave == 0) {
      #pragma unroll
      for (int kt = 0; kt < 2; ++kt)
        #pragma unroll
        for (int nt = 0; nt < 4; ++nt) {
          int n = nt * 16 + lr;
          int k0 = kt * 32 + g * 8;
          float4 lo = *(const float4*)(ew2 + n * 64 + k0);
          float4 hi = *(const float4*)(ew2 + n * 64 + k0 + 4);
          Wlds[0][kt][nt][lane] = make_int4(
              (int)pkbf(lo.x, lo.y), (int)pkbf(lo.z, lo.w),
              (int)pkbf(hi.x, hi.y), (int)pkbf(hi.z, hi.w));
          lo = *(const float4*)(chw + n * 64 + k0);
          hi = *(const float4*)(chw + n * 64 + k0 + 4);
          Wlds[1][kt][nt][lane] = make_int4(
              (int)pkbf(lo.x, lo.y), (int)pkbf(lo.z, lo.w),
              (int)pkbf(hi.x, hi.y), (int)pkbf(hi.z, hi.w));
        }
    }

    // per-lane bias/weight vectors, in registers (n = nt*16 + g*4 + r)
    floatx4 ebr[4], awr[4], chbr[4], cwr[4];
    #pragma unroll
    for (int nt = 0; nt < 4; ++nt) {
      int n4 = nt * 16 + (g << 2);
      ebr[nt]  = *(const floatx4*)(eb2 + n4);
      awr[nt]  = *(const floatx4*)(aw  + n4);
      chbr[nt] = *(const floatx4*)(chb + n4);
      cwr[nt]  = *(const floatx4*)(cww + n4);
    }

    // per-lane ha / wr for this lane's 16 channels: k = kt*32 + g*8 + h*4 + e
    floatx4 har[4], wrr[4];
    #pragma unroll
    for (int kt = 0; kt < 2; ++kt)
      #pragma unroll
      for (int h = 0; h < 2; ++h) {
        int k0 = kt * 32 + g * 8 + h * 4;
        har[kt * 2 + h] = *(const floatx4*)(ha + i0 * 64 + k0);
        floatx4 wv;
        #pragma unroll
        for (int e = 0; e < 4; ++e) {
          float2 w2v = *(const float2*)(ew1 + (k0 + e) * 130 + 128);
          wv[e] = w2v.x + w2v.y;
        }
        wrr[kt * 2 + h] = wv;
      }

    const float L = Lp[0], invL = frcp(L);
    const float ab0 = ab[0];

    floatx4 agg4[4];
    #pragma unroll
    for (int nt = 0; nt < 4; ++nt) agg4[nt] = (floatx4){0.f, 0.f, 0.f, 0.f};
    float dp0 = 0.f, dp1 = 0.f, dp2 = 0.f;

    __syncthreads();

    const float xi0 = xs[i0 * 3 + 0], xi1 = xs[i0 * 3 + 1], xi2 = xs[i0 * 3 + 2];

    // prefetch hb fragment rows for chunk 0 (this lane's edge row lr)
    float4 hpre0, hpre1, hpre2, hpre3;
    {
      const float* hn = hb + (jbase + lr) * 64 + g * 8;
      hpre0 = *(const float4*)(hn);
      hpre1 = *(const float4*)(hn + 4);
      hpre2 = *(const float4*)(hn + 32);
      hpre3 = *(const float4*)(hn + 36);
    }

    for (int jc = 0; jc < 16; ++jc) {
      // laundered lane index: keeps per-chunk weight ds_reads opaque to LICM
      unsigned lidx = (unsigned)lane;
      asm volatile("" : "+v"(lidx));

      float4 h0 = hpre0, h1 = hpre1, h2 = hpre2, h3 = hpre3;
      if (jc < 15) {   // issue next chunk's hb loads NOW; ~200cyc hides under compute
        const float* hn = hb + (jbase + (jc + 1) * 16 + lr) * 64 + g * 8;
        hpre0 = *(const float4*)(hn);
        hpre1 = *(const float4*)(hn + 4);
        hpre2 = *(const float4*)(hn + 32);
        hpre3 = *(const float4*)(hn + 36);
      }

      // ---- geometry for own edge (i0, j): all lanes, row = lr ----
      const int j = jbase + jc * 16 + lr;
      float xd0 = xi0 - xs[j * 3 + 0];
      float xd1 = xi1 - xs[j * 3 + 1];
      float xd2 = xi2 - xs[j * 3 + 2];
      float d0 = xd0 - L * floorf(fmaf(xd0, invL, 0.5f));
      float d1 = xd1 - L * floorf(fmaf(xd1, invL, 0.5f));
      float d2 = xd2 - L * floorf(fmaf(xd2, invL, 0.5f));
      float radial = d0 * d0 + d1 * d1 + d2 * d2;
      float cinv = frcp(__builtin_amdgcn_sqrtf(radial + 1e-8f) + 1.0f);
      float dx0 = d0 * cinv, dx1 = d1 * cinv, dx2 = d2 * cinv;

      // ---- build T fragment in registers: silu(ha + hb + radial*wr) -> bf16 ----
      short8v tf[2];
      {
        floatx4 p0, p1;
        #pragma unroll
        for (int e = 0; e < 4; ++e) {
          p0[e] = fsilu(fmaf(radial, wrr[0][e], har[0][e]) + h0[e]);
          p1[e] = fsilu(fmaf(radial, wrr[1][e], har[1][e]) + h1[e]);
        }
        union { short8v s; unsigned u[4]; } pk;
        pk.u[0] = pkbf(p0[0], p0[1]); pk.u[1] = pkbf(p0[2], p0[3]);
        pk.u[2] = pkbf(p1[0], p1[1]); pk.u[3] = pkbf(p1[2], p1[3]);
        tf[0] = pk.s;
        #pragma unroll
        for (int e = 0; e < 4; ++e) {
          p0[e] = fsilu(fmaf(radial, wrr[2][e], har[2][e]) + h2[e]);
          p1[e] = fsilu(fmaf(radial, wrr[3][e], har[3][e]) + h3[e]);
        }
        pk.u[0] = pkbf(p0[0], p0[1]); pk.u[1] = pkbf(p0[2], p0[3]);
        pk.u[2] = pkbf(p1[0], p1[1]); pk.u[3] = pkbf(p1[2], p1[3]);
        tf[1] = pk.s;
      }

      // ---- GEMM1 (swapped): D1^T = ew2 * T^T ; C-init = eb2 ----
      floatx4 acc[4];
      #pragma unroll
      for (int nt = 0; nt < 4; ++nt) acc[nt] = ebr[nt];
      #pragma unroll
      for (int kt = 0; kt < 2; ++kt)
        #pragma unroll
        for (int nt = 0; nt < 4; ++nt) {
          I4S8 wv; wv.i = WldsF[(kt * 4 + nt) * 64 + lidx];
          acc[nt] = __builtin_amdgcn_mfma_f32_16x16x32_bf16(wv.s, tf[kt], acc[nt], 0, 0, 0);
        }

      // ---- epilogue 1: silu, att (row-dot over n), e, agg ----
      float p = 0.f;
      #pragma unroll
      for (int nt = 0; nt < 4; ++nt)
        #pragma unroll
        for (int r = 0; r < 4; ++r) {
          float s = fsilu(acc[nt][r]);
          acc[nt][r] = s;
          p = fmaf(s, awr[nt][r], p);
        }
      p += __shfl_xor(p, 16); p += __shfl_xor(p, 32);
      const float att = fsig(p + ab0);

      unsigned Pq[4][2];
      #pragma unroll
      for (int nt = 0; nt < 4; ++nt) {
        float e0 = acc[nt][0] * att, e1 = acc[nt][1] * att;
        float e2 = acc[nt][2] * att, e3 = acc[nt][3] * att;
        agg4[nt][0] += e0; agg4[nt][1] += e1;
        agg4[nt][2] += e2; agg4[nt][3] += e3;
        Pq[nt][0] = pkbf(e0, e1);
        Pq[nt][1] = pkbf(e2, e3);
      }

      // ---- assemble GEMM2 B-frags (E^T) in-register via bpermute ----
      union { short8v s; int u[4]; } ef[2];
      #pragma unroll
      for (int kt2 = 0; kt2 < 2; ++kt2)
        #pragma unroll
        for (int w = 0; w < 4; ++w) {
          int sel = (w < 2) ? selA : selB;
          int v0 = __builtin_amdgcn_ds_bpermute(sel, (int)Pq[kt2 * 2][w & 1]);
          int v1 = __builtin_amdgcn_ds_bpermute(sel, (int)Pq[kt2 * 2 + 1][w & 1]);
          ef[kt2].u[w] = ghi ? v1 : v0;
        }

      // ---- GEMM2 (swapped): D2^T = chw * E^T ; C-init = chb (acc reused) ----
      #pragma unroll
      for (int nt = 0; nt < 4; ++nt) acc[nt] = chbr[nt];
      #pragma unroll
      for (int kt2 = 0; kt2 < 2; ++kt2)
        #pragma unroll
        for (int nt = 0; nt < 4; ++nt) {
          I4S8 wv; wv.i = WldsF[512 + (kt2 * 4 + nt) * 64 + lidx];
          acc[nt] = __builtin_amdgcn_mfma_f32_16x16x32_bf16(wv.s, ef[kt2].s, acc[nt], 0, 0, 0);
        }

      // ---- epilogue 2: silu, cww-dot, tanh, delta ----
      float q = 0.f;
      #pragma unroll
      for (int nt = 0; nt < 4; ++nt)
        #pragma unroll
        for (int r = 0; r < 4; ++r)
          q = fmaf(fsilu(acc[nt][r]), cwr[nt][r], q);
      q += __shfl_xor(q, 16); q += __shfl_xor(q, 32);
      const float wvv = ftanh10(q);
      if (g == 0) {
        dp0 = fmaf(dx0, wvv, dp0);
        dp1 = fmaf(dx1, wvv, dp1);
        dp2 = fmaf(dx2, wvv, dp2);
      }
    }

    // ---- final reductions: reduce over edge rows (lr) within wave ----
    #pragma unroll
    for (int nt = 0; nt < 4; ++nt)
      #pragma unroll
      for (int r = 0; r < 4; ++r) {
        float v = agg4[nt][r];
        v += __shfl_xor(v, 1); v += __shfl_xor(v, 2);
        v += __shfl_xor(v, 4); v += __shfl_xor(v, 8);
        agg4[nt][r] = v;
      }
    if (lr == 0) {
      #pragma unroll
      for (int nt = 0; nt < 4; ++nt)
        *(floatx4*)&redagg[wave][nt * 16 + (g << 2)] = agg4[nt];
    }
    dp0 += __shfl_xor(dp0, 1); dp0 += __shfl_xor(dp0, 2); dp0 += __shfl_xor(dp0, 4); dp0 += __shfl_xor(dp0, 8);
    dp1 += __shfl_xor(dp1, 1); dp1 += __shfl_xor(dp1, 2); dp1 += __shfl_xor(dp1, 4); dp1 += __shfl_xor(dp1, 8);
    dp2 += __shfl_xor(dp2, 1); dp2 += __shfl_xor(dp2, 2); dp2 += __shfl_xor(dp2, 4); dp2 += __shfl_xor(dp2, 8);
    if (lane == 0) { sdel[wave][0] = dp0; sdel[wave][1] = dp1; sdel[wave][2] = dp2; }
    __syncthreads();
    if (tid < 64)
      agg[i0 * 64 + tid] = redagg[0][tid] + redagg[1][tid] + redagg[2][tid] + redagg[3][tid];
    else if (tid < 67) {
      int d = tid - 64;
      delta[i0 * 3 + d] = sdel[0][d] + sdel[1][d] + sdel[2][d] + sdel[3][d];
    }
}

// Fused node update + x_new. 256 blocks x 256 thr; block owns 4 nodes.
__global__ __launch_bounds__(256) void node_fused_kernel(
    const float* __restrict__ h, const float* __restrict__ hn1,
    const float* __restrict__ agg, const float* __restrict__ nw1,
    const float* __restrict__ nw2, const float* __restrict__ nb2,
    const float* __restrict__ x, const float* __restrict__ delta,
    const float* __restrict__ Lp, float* __restrict__ outh,
    float* __restrict__ outx)
{
    __shared__ float sps[256];
    const int b = blockIdx.x, tid = threadIdx.x;
    const int gt = b * 256 + tid;
    const int i = gt >> 6, o = gt & 63;
    const float* arow = agg + i * 64;
    const float* wrow = nw1 + o * 128 + 64;
    float acc = hn1[gt];
    #pragma unroll
    for (int k = 0; k < 64; ++k) acc = fmaf(arow[k], wrow[k], acc);
    sps[tid] = fsilu(acc);
    __syncthreads();
    const float* srow = sps + (tid & ~63);
    const float* w2row = nw2 + o * 64;
    float acc2 = h[gt] + nb2[o];
    #pragma unroll
    for (int k = 0; k < 64; ++k) acc2 = fmaf(srow[k], w2row[k], acc2);
    outh[gt] = acc2;
    if (tid < 12) {
        int ii = b * 4 + tid / 3, d = tid % 3;
        float L = Lp[0];
        float v = x[ii * 3 + d] + delta[ii * 3 + d];
        outx[ii * 3 + d] = v - L * floorf(v * frcp(L));
    }
}

extern "C" void kernel_launch(void* const* d_in, const int* in_sizes, int n_in,
                              void* d_out, int out_size, void* d_ws, size_t ws_size,
                              hipStream_t stream) {
    const float* h   = (const float*)d_in[0];
    const float* x   = (const float*)d_in[1];
    const float* Lp  = (const float*)d_in[2];
    const float* ew1 = (const float*)d_in[3];
    const float* eb1 = (const float*)d_in[4];
    const float* ew2 = (const float*)d_in[5];
    const float* eb2 = (const float*)d_in[6];
    const float* nw1 = (const float*)d_in[7];
    const float* nb1 = (const float*)d_in[8];
    const float* nw2 = (const float*)d_in[9];
    const float* nb2 = (const float*)d_in[10];
    const float* chw = (const float*)d_in[11];
    const float* chb = (const float*)d_in[12];
    const float* cww = (const float*)d_in[13];
    const float* aw  = (const float*)d_in[14];
    const float* ab  = (const float*)d_in[15];

    float* ws    = (float*)d_ws;
    float* ha    = ws;             // 65536
    float* hb    = ws + 65536;     // 65536
    float* hn1   = ws + 131072;    // 65536
    float* agg   = ws + 196608;    // 65536
    float* delta = ws + 262144;    // 3072

    float* outh = (float*)d_out;       // 65536
    float* outx = outh + 65536;        // 3072

    precompute_kernel<<<768, 256, 0, stream>>>(h, ew1, eb1, nw1, nb1, ha, hb, hn1);
    edge_mfma_kernel<<<1024, 256, 0, stream>>>(x, Lp, ha, hb, ew1, ew2, eb2, chw, chb,
                                               aw, ab, cww, agg, delta);
    node_fused_kernel<<<256, 256, 0, stream>>>(h, hn1, agg, nw1, nw2, nb2, x, delta,
                                               Lp, outh, outx);
}

// Round 11
// 93.313 us; speedup vs baseline: 3.1088x; 1.0197x over previous
//
#include <hip/hip_runtime.h>

#define Nn 1024

typedef __attribute__((ext_vector_type(8))) short short8v;
typedef __attribute__((ext_vector_type(4))) float floatx4;

// hardware-rate reciprocal / sqrt (v_rcp_f32 / v_sqrt_f32, ~1ulp).
__device__ __forceinline__ float frcp(float v)  { return __builtin_amdgcn_rcpf(v); }
__device__ __forceinline__ float fsilu(float v) { return v * frcp(1.0f + __expf(-v)); }
__device__ __forceinline__ float fsig(float v)  { return frcp(1.0f + __expf(-v)); }
__device__ __forceinline__ float ftanh10(float v){ return 10.0f - 20.0f * frcp(__expf(2.0f * v) + 1.0f); }

// 2x f32 -> packed bf16 (RNE) in ONE instruction (no builtin on gfx950 — T12)
__device__ __forceinline__ unsigned cvtpk(float lo, float hi) {
    unsigned r;
    asm("v_cvt_pk_bf16_f32 %0, %1, %2" : "=v"(r) : "v"(lo), "v"(hi));
    return r;
}

union I4S8 { int4 i; short8v s; };

// Kernel A: ha = h@Wa^T + eb1 ; hb = h@Wb^T ; hn1 = h@nw1[:, :64]^T + nb1
__global__ __launch_bounds__(256) void precompute_kernel(
    const float* __restrict__ h, const float* __restrict__ ew1,
    const float* __restrict__ eb1, const float* __restrict__ nw1,
    const float* __restrict__ nb1, float* __restrict__ ha,
    float* __restrict__ hb, float* __restrict__ hn1)
{
    int t = blockIdx.x * 256 + threadIdx.x;
    int which = t >> 16;
    int rem = t & 65535;
    int i = rem >> 6, o = rem & 63;
    const float* hrow = h + i * 64;
    const float* wrow;
    float acc;
    if (which == 0)      { wrow = ew1 + o * 130;      acc = eb1[o]; }
    else if (which == 1) { wrow = ew1 + o * 130 + 64; acc = 0.0f;   }
    else                 { wrow = nw1 + o * 128;      acc = nb1[o]; }
    #pragma unroll
    for (int k = 0; k < 64; ++k) acc = fmaf(hrow[k], wrow[k], acc);
    if (which == 0)      ha[rem]  = acc;
    else if (which == 1) hb[rem]  = acc;
    else                 hn1[rem] = acc;
}

// Edge pipeline. 1024 blocks x 256 thr (4 waves): block owns node i0 = blockIdx.x,
// wave w owns j-quarter in 16 chunks of 16 edges. Chunk loop is wave-private.
// Both GEMMs computed swapped: D^T = W * T^T, output col = edge row = lane&15.
// R11: ALL loop-invariant per-lane constants (eb2/aw/chb/cww + ha-row/wr-row,
// ~96 regs in R10) moved to LDS (cvec) and re-read per chunk via laundered
// base + compile-time ds offsets. Unified VGPR+AGPR footprint drops from
// ~160-190 (2-3 waves/SIMD, R10's occupancy ceiling) to ~100 -> 4 waves/SIMD.
// bf16 packing via single v_cvt_pk_bf16_f32 instead of 3-op bit trick.
__global__ __launch_bounds__(256) __attribute__((amdgpu_waves_per_eu(3, 4)))
void edge_mfma_kernel(
    const float* __restrict__ x, const float* __restrict__ Lp,
    const float* __restrict__ ha, const float* __restrict__ hb,
    const float* __restrict__ ew1, const float* __restrict__ ew2,
    const float* __restrict__ eb2, const float* __restrict__ chw,
    const float* __restrict__ chb, const float* __restrict__ aw,
    const float* __restrict__ ab, const float* __restrict__ cww,
    float* __restrict__ agg, float* __restrict__ delta)
{
    __shared__ __align__(16) int4 Wlds[1024];     // [w2|wc][kt][nt][lane] packed bf16 frags, 16KB
    __shared__ __align__(16) float cvec[384];     // eb2|aw|chb|cww|ha_row|wr_row (64 each)
    __shared__ __align__(16) float xs[Nn * 3];
    __shared__ float redagg[4][64];
    __shared__ float sdel[4][3];

    const int tid  = threadIdx.x;
    const int wave = tid >> 6, lane = tid & 63;
    const int lr = lane & 15, g = lane >> 4;
    const int i0 = blockIdx.x;
    const int jbase = wave * 256;
    const int ghi  = g >> 1;
    const int selA = (lr + ((g & 1) << 5)) << 2;   // bpermute byte addr
    const int selB = selA + 64;
    const int4* WldsF = &Wlds[0];

    // stage x into LDS (float4)
    {
        const float4* xsrc = (const float4*)x;
        float4* xdst = (float4*)xs;
        xdst[tid] = xsrc[tid];
        xdst[tid + 256] = xsrc[tid + 256];
        xdst[tid + 512] = xsrc[tid + 512];
    }

    // wave 0 stages packed weight fragments into LDS: row n = lane&15, k 8-contig per g.
    if (wave == 0) {
      #pragma unroll
      for (int kt = 0; kt < 2; ++kt)
        #pragma unroll
        for (int nt = 0; nt < 4; ++nt) {
          int n = nt * 16 + lr;
          int k0 = kt * 32 + g * 8;
          float4 lo = *(const float4*)(ew2 + n * 64 + k0);
          float4 hi = *(const float4*)(ew2 + n * 64 + k0 + 4);
          Wlds[(kt * 4 + nt) * 64 + lane] = make_int4(
              (int)cvtpk(lo.x, lo.y), (int)cvtpk(lo.z, lo.w),
              (int)cvtpk(hi.x, hi.y), (int)cvtpk(hi.z, hi.w));
          lo = *(const float4*)(chw + n * 64 + k0);
          hi = *(const float4*)(chw + n * 64 + k0 + 4);
          Wlds[512 + (kt * 4 + nt) * 64 + lane] = make_int4(
              (int)cvtpk(lo.x, lo.y), (int)cvtpk(lo.z, lo.w),
              (int)cvtpk(hi.x, hi.y), (int)cvtpk(hi.z, hi.w));
        }
    }
    // constant vectors -> LDS (re-read per chunk; keeps them out of registers)
    if (tid < 64) {
      cvec[tid]       = eb2[tid];
      cvec[64 + tid]  = aw[tid];
      cvec[128 + tid] = chb[tid];
      cvec[192 + tid] = cww[tid];
      cvec[256 + tid] = ha[i0 * 64 + tid];
      cvec[320 + tid] = ew1[tid * 130 + 128] + ew1[tid * 130 + 129];
    }

    const float L = Lp[0], invL = frcp(L);
    const float ab0 = ab[0];

    floatx4 agg4[4];
    #pragma unroll
    for (int nt = 0; nt < 4; ++nt) agg4[nt] = (floatx4){0.f, 0.f, 0.f, 0.f};
    float dp0 = 0.f, dp1 = 0.f, dp2 = 0.f;

    __syncthreads();

    const float xi0 = xs[i0 * 3 + 0], xi1 = xs[i0 * 3 + 1], xi2 = xs[i0 * 3 + 2];

    // prefetch hb fragment rows for chunk 0 (this lane's edge row lr)
    float4 hpre0, hpre1, hpre2, hpre3;
    {
      const float* hn = hb + (jbase + lr) * 64 + g * 8;
      hpre0 = *(const float4*)(hn);
      hpre1 = *(const float4*)(hn + 4);
      hpre2 = *(const float4*)(hn + 32);
      hpre3 = *(const float4*)(hn + 36);
    }

    for (int jc = 0; jc < 16; ++jc) {
      // laundered indices: keep per-chunk LDS reads opaque to LICM
      unsigned lidx = (unsigned)lane;
      asm volatile("" : "+v"(lidx));
      unsigned cb = (unsigned)(g << 4);          // g*4 floats (bias vectors)
      asm volatile("" : "+v"(cb));
      unsigned hbo = (unsigned)(g << 5);         // g*8 floats (ha/wr rows)
      asm volatile("" : "+v"(hbo));
      const float* cvp = (const float*)((const char*)cvec + cb);
      const float* hvp = (const float*)((const char*)cvec + 1024 + hbo);

      float4 h0 = hpre0, h1 = hpre1, h2 = hpre2, h3 = hpre3;
      if (jc < 15) {   // issue next chunk's hb loads NOW; L2 latency hides under compute
        const float* hn = hb + (jbase + (jc + 1) * 16 + lr) * 64 + g * 8;
        hpre0 = *(const float4*)(hn);
        hpre1 = *(const float4*)(hn + 4);
        hpre2 = *(const float4*)(hn + 32);
        hpre3 = *(const float4*)(hn + 36);
      }

      // ---- geometry for own edge (i0, j): all lanes, row = lr ----
      const int j = jbase + jc * 16 + lr;
      float xd0 = xi0 - xs[j * 3 + 0];
      float xd1 = xi1 - xs[j * 3 + 1];
      float xd2 = xi2 - xs[j * 3 + 2];
      float d0 = xd0 - L * floorf(fmaf(xd0, invL, 0.5f));
      float d1 = xd1 - L * floorf(fmaf(xd1, invL, 0.5f));
      float d2 = xd2 - L * floorf(fmaf(xd2, invL, 0.5f));
      float radial = d0 * d0 + d1 * d1 + d2 * d2;
      float cinv = frcp(__builtin_amdgcn_sqrtf(radial + 1e-8f) + 1.0f);
      float dx0 = d0 * cinv, dx1 = d1 * cinv, dx2 = d2 * cinv;

      // ---- build T fragment in registers: silu(ha + hb + radial*wr) -> bf16 ----
      short8v tf[2];
      {
        union { short8v s; unsigned u[4]; } pk;
        #pragma unroll
        for (int kt = 0; kt < 2; ++kt) {
          floatx4 ha0 = *(const floatx4*)(hvp + kt * 32);
          floatx4 ha1 = *(const floatx4*)(hvp + kt * 32 + 4);
          floatx4 wr0 = *(const floatx4*)(hvp + 64 + kt * 32);
          floatx4 wr1 = *(const floatx4*)(hvp + 64 + kt * 32 + 4);
          const float4& hA = kt ? h2 : h0;
          const float4& hB = kt ? h3 : h1;
          floatx4 p0, p1;
          p0[0] = fsilu(fmaf(radial, wr0[0], ha0[0]) + hA.x);
          p0[1] = fsilu(fmaf(radial, wr0[1], ha0[1]) + hA.y);
          p0[2] = fsilu(fmaf(radial, wr0[2], ha0[2]) + hA.z);
          p0[3] = fsilu(fmaf(radial, wr0[3], ha0[3]) + hA.w);
          p1[0] = fsilu(fmaf(radial, wr1[0], ha1[0]) + hB.x);
          p1[1] = fsilu(fmaf(radial, wr1[1], ha1[1]) + hB.y);
          p1[2] = fsilu(fmaf(radial, wr1[2], ha1[2]) + hB.z);
          p1[3] = fsilu(fmaf(radial, wr1[3], ha1[3]) + hB.w);
          pk.u[0] = cvtpk(p0[0], p0[1]); pk.u[1] = cvtpk(p0[2], p0[3]);
          pk.u[2] = cvtpk(p1[0], p1[1]); pk.u[3] = cvtpk(p1[2], p1[3]);
          tf[kt] = pk.s;
        }
      }

      // ---- GEMM1 (swapped): D1^T = ew2 * T^T ; C-init = eb2 (from LDS) ----
      floatx4 acc[4];
      #pragma unroll
      for (int nt = 0; nt < 4; ++nt) acc[nt] = *(const floatx4*)(cvp + nt * 16);
      #pragma unroll
      for (int kt = 0; kt < 2; ++kt)
        #pragma unroll
        for (int nt = 0; nt < 4; ++nt) {
          I4S8 wv; wv.i = WldsF[(kt * 4 + nt) * 64 + lidx];
          acc[nt] = __builtin_amdgcn_mfma_f32_16x16x32_bf16(wv.s, tf[kt], acc[nt], 0, 0, 0);
        }

      // ---- epilogue 1: silu, att (row-dot over n), e, agg ----
      float p = 0.f;
      #pragma unroll
      for (int nt = 0; nt < 4; ++nt) {
        floatx4 awv = *(const floatx4*)(cvp + 64 + nt * 16);
        #pragma unroll
        for (int r = 0; r < 4; ++r) {
          float s = fsilu(acc[nt][r]);
          acc[nt][r] = s;
          p = fmaf(s, awv[r], p);
        }
      }
      p += __shfl_xor(p, 16); p += __shfl_xor(p, 32);
      const float att = fsig(p + ab0);

      unsigned Pq[4][2];
      #pragma unroll
      for (int nt = 0; nt < 4; ++nt) {
        float e0 = acc[nt][0] * att, e1 = acc[nt][1] * att;
        float e2 = acc[nt][2] * att, e3 = acc[nt][3] * att;
        agg4[nt][0] += e0; agg4[nt][1] += e1;
        agg4[nt][2] += e2; agg4[nt][3] += e3;
        Pq[nt][0] = cvtpk(e0, e1);
        Pq[nt][1] = cvtpk(e2, e3);
      }

      // ---- assemble GEMM2 B-frags (E^T) in-register via bpermute ----
      union { short8v s; int u[4]; } ef[2];
      #pragma unroll
      for (int kt2 = 0; kt2 < 2; ++kt2)
        #pragma unroll
        for (int w = 0; w < 4; ++w) {
          int sel = (w < 2) ? selA : selB;
          int v0 = __builtin_amdgcn_ds_bpermute(sel, (int)Pq[kt2 * 2][w & 1]);
          int v1 = __builtin_amdgcn_ds_bpermute(sel, (int)Pq[kt2 * 2 + 1][w & 1]);
          ef[kt2].u[w] = ghi ? v1 : v0;
        }

      // ---- GEMM2 (swapped): D2^T = chw * E^T ; C-init = chb (from LDS) ----
      #pragma unroll
      for (int nt = 0; nt < 4; ++nt) acc[nt] = *(const floatx4*)(cvp + 128 + nt * 16);
      #pragma unroll
      for (int kt2 = 0; kt2 < 2; ++kt2)
        #pragma unroll
        for (int nt = 0; nt < 4; ++nt) {
          I4S8 wv; wv.i = WldsF[512 + (kt2 * 4 + nt) * 64 + lidx];
          acc[nt] = __builtin_amdgcn_mfma_f32_16x16x32_bf16(wv.s, ef[kt2].s, acc[nt], 0, 0, 0);
        }

      // ---- epilogue 2: silu, cww-dot, tanh, delta ----
      float q = 0.f;
      #pragma unroll
      for (int nt = 0; nt < 4; ++nt) {
        floatx4 cwv = *(const floatx4*)(cvp + 192 + nt * 16);
        #pragma unroll
        for (int r = 0; r < 4; ++r)
          q = fmaf(fsilu(acc[nt][r]), cwv[r], q);
      }
      q += __shfl_xor(q, 16); q += __shfl_xor(q, 32);
      const float wvv = ftanh10(q);
      if (g == 0) {
        dp0 = fmaf(dx0, wvv, dp0);
        dp1 = fmaf(dx1, wvv, dp1);
        dp2 = fmaf(dx2, wvv, dp2);
      }
    }

    // ---- final reductions: reduce over edge rows (lr) within wave ----
    #pragma unroll
    for (int nt = 0; nt < 4; ++nt)
      #pragma unroll
      for (int r = 0; r < 4; ++r) {
        float v = agg4[nt][r];
        v += __shfl_xor(v, 1); v += __shfl_xor(v, 2);
        v += __shfl_xor(v, 4); v += __shfl_xor(v, 8);
        agg4[nt][r] = v;
      }
    if (lr == 0) {
      #pragma unroll
      for (int nt = 0; nt < 4; ++nt)
        *(floatx4*)&redagg[wave][nt * 16 + (g << 2)] = agg4[nt];
    }
    dp0 += __shfl_xor(dp0, 1); dp0 += __shfl_xor(dp0, 2); dp0 += __shfl_xor(dp0, 4); dp0 += __shfl_xor(dp0, 8);
    dp1 += __shfl_xor(dp1, 1); dp1 += __shfl_xor(dp1, 2); dp1 += __shfl_xor(dp1, 4); dp1 += __shfl_xor(dp1, 8);
    dp2 += __shfl_xor(dp2, 1); dp2 += __shfl_xor(dp2, 2); dp2 += __shfl_xor(dp2, 4); dp2 += __shfl_xor(dp2, 8);
    if (lane == 0) { sdel[wave][0] = dp0; sdel[wave][1] = dp1; sdel[wave][2] = dp2; }
    __syncthreads();
    if (tid < 64)
      agg[i0 * 64 + tid] = redagg[0][tid] + redagg[1][tid] + redagg[2][tid] + redagg[3][tid];
    else if (tid < 67) {
      int d = tid - 64;
      delta[i0 * 3 + d] = sdel[0][d] + sdel[1][d] + sdel[2][d] + sdel[3][d];
    }
}

// Fused node update + x_new. 256 blocks x 256 thr; block owns 4 nodes.
__global__ __launch_bounds__(256) void node_fused_kernel(
    const float* __restrict__ h, const float* __restrict__ hn1,
    const float* __restrict__ agg, const float* __restrict__ nw1,
    const float* __restrict__ nw2, const float* __restrict__ nb2,
    const float* __restrict__ x, const float* __restrict__ delta,
    const float* __restrict__ Lp, float* __restrict__ outh,
    float* __restrict__ outx)
{
    __shared__ float sps[256];
    const int b = blockIdx.x, tid = threadIdx.x;
    const int gt = b * 256 + tid;
    const int i = gt >> 6, o = gt & 63;
    const float* arow = agg + i * 64;
    const float* wrow = nw1 + o * 128 + 64;
    float acc = hn1[gt];
    #pragma unroll
    for (int k = 0; k < 64; ++k) acc = fmaf(arow[k], wrow[k], acc);
    sps[tid] = fsilu(acc);
    __syncthreads();
    const float* srow = sps + (tid & ~63);
    const float* w2row = nw2 + o * 64;
    float acc2 = h[gt] + nb2[o];
    #pragma unroll
    for (int k = 0; k < 64; ++k) acc2 = fmaf(srow[k], w2row[k], acc2);
    outh[gt] = acc2;
    if (tid < 12) {
        int ii = b * 4 + tid / 3, d = tid % 3;
        float L = Lp[0];
        float v = x[ii * 3 + d] + delta[ii * 3 + d];
        outx[ii * 3 + d] = v - L * floorf(v * frcp(L));
    }
}

extern "C" void kernel_launch(void* const* d_in, const int* in_sizes, int n_in,
                              void* d_out, int out_size, void* d_ws, size_t ws_size,
                              hipStream_t stream) {
    const float* h   = (const float*)d_in[0];
    const float* x   = (const float*)d_in[1];
    const float* Lp  = (const float*)d_in[2];
    const float* ew1 = (const float*)d_in[3];
    const float* eb1 = (const float*)d_in[4];
    const float* ew2 = (const float*)d_in[5];
    const float* eb2 = (const float*)d_in[6];
    const float* nw1 = (const float*)d_in[7];
    const float* nb1 = (const float*)d_in[8];
    const float* nw2 = (const float*)d_in[9];
    const float* nb2 = (const float*)d_in[10];
    const float* chw = (const float*)d_in[11];
    const float* chb = (const float*)d_in[12];
    const float* cww = (const float*)d_in[13];
    const float* aw  = (const float*)d_in[14];
    const float* ab  = (const float*)d_in[15];

    float* ws    = (float*)d_ws;
    float* ha    = ws;             // 65536
    float* hb    = ws + 65536;     // 65536
    float* hn1   = ws + 131072;    // 65536
    float* agg   = ws + 196608;    // 65536
    float* delta = ws + 262144;    // 3072

    float* outh = (float*)d_out;       // 65536
    float* outx = outh + 65536;        // 3072

    precompute_kernel<<<768, 256, 0, stream>>>(h, ew1, eb1, nw1, nb1, ha, hb, hn1);
    edge_mfma_kernel<<<1024, 256, 0, stream>>>(x, Lp, ha, hb, ew1, ew2, eb2, chw, chb,
                                               aw, ab, cww, agg, delta);
    node_fused_kernel<<<256, 256, 0, stream>>>(h, hn1, agg, nw1, nw2, nb2, x, delta,
                                               Lp, outh, outx);
}

// Round 13
// 90.776 us; speedup vs baseline: 3.1958x; 1.0280x over previous
//
#include <hip/hip_runtime.h>

#define Nn 1024

typedef __attribute__((ext_vector_type(8))) short short8v;
typedef __attribute__((ext_vector_type(4))) float floatx4;

// hardware-rate reciprocal / sqrt (v_rcp_f32 / v_sqrt_f32, ~1ulp).
__device__ __forceinline__ float frcp(float v)  { return __builtin_amdgcn_rcpf(v); }
__device__ __forceinline__ float fsilu(float v) { return v * frcp(1.0f + __expf(-v)); }
__device__ __forceinline__ float fsig(float v)  { return frcp(1.0f + __expf(-v)); }
__device__ __forceinline__ float ftanh10(float v){ return 10.0f - 20.0f * frcp(__expf(2.0f * v) + 1.0f); }

// 2x f32 -> packed bf16 (RNE) in ONE instruction (no builtin on gfx950 — T12)
__device__ __forceinline__ unsigned cvtpk(float lo, float hi) {
    unsigned r;
    asm("v_cvt_pk_bf16_f32 %0, %1, %2" : "=v"(r) : "v"(lo), "v"(hi));
    return r;
}

union I4S8 { int4 i; short8v s; };

// Kernel A: ha = h@Wa^T + eb1 ; hb = h@Wb^T   (hn1 folded into node_fused)
__global__ __launch_bounds__(256) void precompute_kernel(
    const float* __restrict__ h, const float* __restrict__ ew1,
    const float* __restrict__ eb1, float* __restrict__ ha,
    float* __restrict__ hb)
{
    int t = blockIdx.x * 256 + threadIdx.x;   // 0 .. 2*65536-1
    int which = t >> 16;
    int rem = t & 65535;
    int i = rem >> 6, o = rem & 63;
    const float* hrow = h + i * 64;
    const float* wrow;
    float acc;
    if (which == 0) { wrow = ew1 + o * 130;      acc = eb1[o]; }
    else            { wrow = ew1 + o * 130 + 64; acc = 0.0f;   }
    #pragma unroll
    for (int k = 0; k < 64; ++k) acc = fmaf(hrow[k], wrow[k], acc);
    if (which == 0) ha[rem] = acc;
    else            hb[rem] = acc;
}

// Edge pipeline. 2048 blocks x 256 thr (4 waves): block b owns node b>>1 and
// j-half b&1; wave owns 128 j's in 8 chunks of 16. Inner loop is the R11 body
// verbatim (proven); outputs go to per-half partial buffers (no cross-block
// races), summed in node_fused. xs LDS mirror dropped (x is 12KB, L1-hot) ->
// LDS ~19KB -> 8 blocks/CU; 2048x4 waves = full 8192-slot co-residency.
// waves_per_eu(4,8): min4 = 128-reg budget (no forced spill), max 8 at VGPR=64.
__global__ __launch_bounds__(256) __attribute__((amdgpu_waves_per_eu(4, 8)))
void edge_mfma_kernel(
    const float* __restrict__ x, const float* __restrict__ Lp,
    const float* __restrict__ ha, const float* __restrict__ hb,
    const float* __restrict__ ew1, const float* __restrict__ ew2,
    const float* __restrict__ eb2, const float* __restrict__ chw,
    const float* __restrict__ chb, const float* __restrict__ aw,
    const float* __restrict__ ab, const float* __restrict__ cww,
    float* __restrict__ agg_parts, float* __restrict__ delta_parts)
{
    __shared__ __align__(16) int4 Wlds[1024];     // [w2|wc][kt][nt][lane] packed bf16 frags, 16KB
    __shared__ __align__(16) float cvec[384];     // eb2|aw|chb|cww|ha_row|wr_row (64 each)
    __shared__ float redagg[4][64];
    __shared__ float sdel[4][3];

    const int tid  = threadIdx.x;
    const int wave = tid >> 6, lane = tid & 63;
    const int lr = lane & 15, g = lane >> 4;
    const int i0 = blockIdx.x >> 1;
    const int half = blockIdx.x & 1;
    const int jbase = half * 512 + wave * 128;
    const int ghi  = g >> 1;
    const int selA = (lr + ((g & 1) << 5)) << 2;   // bpermute byte addr
    const int selB = selA + 64;
    const int4* WldsF = &Wlds[0];

    // wave 0 stages packed weight fragments into LDS: row n = lane&15, k 8-contig per g.
    if (wave == 0) {
      #pragma unroll
      for (int kt = 0; kt < 2; ++kt)
        #pragma unroll
        for (int nt = 0; nt < 4; ++nt) {
          int n = nt * 16 + lr;
          int k0 = kt * 32 + g * 8;
          float4 lo = *(const float4*)(ew2 + n * 64 + k0);
          float4 hi = *(const float4*)(ew2 + n * 64 + k0 + 4);
          Wlds[(kt * 4 + nt) * 64 + lane] = make_int4(
              (int)cvtpk(lo.x, lo.y), (int)cvtpk(lo.z, lo.w),
              (int)cvtpk(hi.x, hi.y), (int)cvtpk(hi.z, hi.w));
          lo = *(const float4*)(chw + n * 64 + k0);
          hi = *(const float4*)(chw + n * 64 + k0 + 4);
          Wlds[512 + (kt * 4 + nt) * 64 + lane] = make_int4(
              (int)cvtpk(lo.x, lo.y), (int)cvtpk(lo.z, lo.w),
              (int)cvtpk(hi.x, hi.y), (int)cvtpk(hi.z, hi.w));
        }
    }
    // constant vectors -> LDS (re-read per chunk; keeps them out of registers)
    if (tid < 64) {
      cvec[tid]       = eb2[tid];
      cvec[64 + tid]  = aw[tid];
      cvec[128 + tid] = chb[tid];
      cvec[192 + tid] = cww[tid];
      cvec[256 + tid] = ha[i0 * 64 + tid];
      cvec[320 + tid] = ew1[tid * 130 + 128] + ew1[tid * 130 + 129];
    }

    const float L = Lp[0], invL = frcp(L);
    const float ab0 = ab[0];

    floatx4 agg4[4];
    #pragma unroll
    for (int nt = 0; nt < 4; ++nt) agg4[nt] = (floatx4){0.f, 0.f, 0.f, 0.f};
    float dp0 = 0.f, dp1 = 0.f, dp2 = 0.f;

    __syncthreads();

    const float xi0 = x[i0 * 3 + 0], xi1 = x[i0 * 3 + 1], xi2 = x[i0 * 3 + 2];

    // prefetch hb fragment rows for chunk 0 (this lane's edge row lr)
    float4 hpre0, hpre1, hpre2, hpre3;
    {
      const float* hn = hb + (jbase + lr) * 64 + g * 8;
      hpre0 = *(const float4*)(hn);
      hpre1 = *(const float4*)(hn + 4);
      hpre2 = *(const float4*)(hn + 32);
      hpre3 = *(const float4*)(hn + 36);
    }

    for (int jc = 0; jc < 8; ++jc) {
      // laundered indices: keep per-chunk LDS reads opaque to LICM
      unsigned lidx = (unsigned)lane;
      asm volatile("" : "+v"(lidx));
      unsigned cb = (unsigned)(g << 4);          // g*4 floats (bias vectors)
      asm volatile("" : "+v"(cb));
      unsigned hbo = (unsigned)(g << 5);         // g*8 floats (ha/wr rows)
      asm volatile("" : "+v"(hbo));
      const float* cvp = (const float*)((const char*)cvec + cb);
      const float* hvp = (const float*)((const char*)cvec + 1024 + hbo);

      float4 h0 = hpre0, h1 = hpre1, h2 = hpre2, h3 = hpre3;
      if (jc < 7) {   // issue next chunk's hb loads NOW; L2 latency hides under compute
        const float* hn = hb + (jbase + (jc + 1) * 16 + lr) * 64 + g * 8;
        hpre0 = *(const float4*)(hn);
        hpre1 = *(const float4*)(hn + 4);
        hpre2 = *(const float4*)(hn + 32);
        hpre3 = *(const float4*)(hn + 36);
      }

      // ---- geometry for own edge (i0, j): all lanes, row = lr (x is L1-hot) ----
      const int j = jbase + jc * 16 + lr;
      float xd0 = xi0 - x[j * 3 + 0];
      float xd1 = xi1 - x[j * 3 + 1];
      float xd2 = xi2 - x[j * 3 + 2];
      float d0 = xd0 - L * floorf(fmaf(xd0, invL, 0.5f));
      float d1 = xd1 - L * floorf(fmaf(xd1, invL, 0.5f));
      float d2 = xd2 - L * floorf(fmaf(xd2, invL, 0.5f));
      float radial = d0 * d0 + d1 * d1 + d2 * d2;
      float cinv = frcp(__builtin_amdgcn_sqrtf(radial + 1e-8f) + 1.0f);
      float dx0 = d0 * cinv, dx1 = d1 * cinv, dx2 = d2 * cinv;

      // ---- build T fragment in registers: silu(ha + hb + radial*wr) -> bf16 ----
      short8v tf[2];
      {
        union { short8v s; unsigned u[4]; } pk;
        #pragma unroll
        for (int kt = 0; kt < 2; ++kt) {
          floatx4 ha0 = *(const floatx4*)(hvp + kt * 32);
          floatx4 ha1 = *(const floatx4*)(hvp + kt * 32 + 4);
          floatx4 wr0 = *(const floatx4*)(hvp + 64 + kt * 32);
          floatx4 wr1 = *(const floatx4*)(hvp + 64 + kt * 32 + 4);
          const float4& hA = kt ? h2 : h0;
          const float4& hB = kt ? h3 : h1;
          floatx4 p0, p1;
          p0[0] = fsilu(fmaf(radial, wr0[0], ha0[0]) + hA.x);
          p0[1] = fsilu(fmaf(radial, wr0[1], ha0[1]) + hA.y);
          p0[2] = fsilu(fmaf(radial, wr0[2], ha0[2]) + hA.z);
          p0[3] = fsilu(fmaf(radial, wr0[3], ha0[3]) + hA.w);
          p1[0] = fsilu(fmaf(radial, wr1[0], ha1[0]) + hB.x);
          p1[1] = fsilu(fmaf(radial, wr1[1], ha1[1]) + hB.y);
          p1[2] = fsilu(fmaf(radial, wr1[2], ha1[2]) + hB.z);
          p1[3] = fsilu(fmaf(radial, wr1[3], ha1[3]) + hB.w);
          pk.u[0] = cvtpk(p0[0], p0[1]); pk.u[1] = cvtpk(p0[2], p0[3]);
          pk.u[2] = cvtpk(p1[0], p1[1]); pk.u[3] = cvtpk(p1[2], p1[3]);
          tf[kt] = pk.s;
        }
      }

      // ---- GEMM1 (swapped): D1^T = ew2 * T^T ; C-init = eb2 (from LDS) ----
      floatx4 acc[4];
      #pragma unroll
      for (int nt = 0; nt < 4; ++nt) acc[nt] = *(const floatx4*)(cvp + nt * 16);
      #pragma unroll
      for (int kt = 0; kt < 2; ++kt)
        #pragma unroll
        for (int nt = 0; nt < 4; ++nt) {
          I4S8 wv; wv.i = WldsF[(kt * 4 + nt) * 64 + lidx];
          acc[nt] = __builtin_amdgcn_mfma_f32_16x16x32_bf16(wv.s, tf[kt], acc[nt], 0, 0, 0);
        }

      // ---- epilogue 1: silu, att (row-dot over n), e, agg ----
      float p = 0.f;
      #pragma unroll
      for (int nt = 0; nt < 4; ++nt) {
        floatx4 awv = *(const floatx4*)(cvp + 64 + nt * 16);
        #pragma unroll
        for (int r = 0; r < 4; ++r) {
          float s = fsilu(acc[nt][r]);
          acc[nt][r] = s;
          p = fmaf(s, awv[r], p);
        }
      }
      p += __shfl_xor(p, 16); p += __shfl_xor(p, 32);
      const float att = fsig(p + ab0);

      unsigned Pq[4][2];
      #pragma unroll
      for (int nt = 0; nt < 4; ++nt) {
        float e0 = acc[nt][0] * att, e1 = acc[nt][1] * att;
        float e2 = acc[nt][2] * att, e3 = acc[nt][3] * att;
        agg4[nt][0] += e0; agg4[nt][1] += e1;
        agg4[nt][2] += e2; agg4[nt][3] += e3;
        Pq[nt][0] = cvtpk(e0, e1);
        Pq[nt][1] = cvtpk(e2, e3);
      }

      // ---- assemble GEMM2 B-frags (E^T) in-register via bpermute ----
      union { short8v s; int u[4]; } ef[2];
      #pragma unroll
      for (int kt2 = 0; kt2 < 2; ++kt2)
        #pragma unroll
        for (int w = 0; w < 4; ++w) {
          int sel = (w < 2) ? selA : selB;
          int v0 = __builtin_amdgcn_ds_bpermute(sel, (int)Pq[kt2 * 2][w & 1]);
          int v1 = __builtin_amdgcn_ds_bpermute(sel, (int)Pq[kt2 * 2 + 1][w & 1]);
          ef[kt2].u[w] = ghi ? v1 : v0;
        }

      // ---- GEMM2 (swapped): D2^T = chw * E^T ; C-init = chb (from LDS) ----
      #pragma unroll
      for (int nt = 0; nt < 4; ++nt) acc[nt] = *(const floatx4*)(cvp + 128 + nt * 16);
      #pragma unroll
      for (int kt2 = 0; kt2 < 2; ++kt2)
        #pragma unroll
        for (int nt = 0; nt < 4; ++nt) {
          I4S8 wv; wv.i = WldsF[512 + (kt2 * 4 + nt) * 64 + lidx];
          acc[nt] = __builtin_amdgcn_mfma_f32_16x16x32_bf16(wv.s, ef[kt2].s, acc[nt], 0, 0, 0);
        }

      // ---- epilogue 2: silu, cww-dot, tanh, delta ----
      float q = 0.f;
      #pragma unroll
      for (int nt = 0; nt < 4; ++nt) {
        floatx4 cwv = *(const floatx4*)(cvp + 192 + nt * 16);
        #pragma unroll
        for (int r = 0; r < 4; ++r)
          q = fmaf(fsilu(acc[nt][r]), cwv[r], q);
      }
      q += __shfl_xor(q, 16); q += __shfl_xor(q, 32);
      const float wvv = ftanh10(q);
      if (g == 0) {
        dp0 = fmaf(dx0, wvv, dp0);
        dp1 = fmaf(dx1, wvv, dp1);
        dp2 = fmaf(dx2, wvv, dp2);
      }
    }

    // ---- final reductions: reduce over edge rows (lr) within wave ----
    #pragma unroll
    for (int nt = 0; nt < 4; ++nt)
      #pragma unroll
      for (int r = 0; r < 4; ++r) {
        float v = agg4[nt][r];
        v += __shfl_xor(v, 1); v += __shfl_xor(v, 2);
        v += __shfl_xor(v, 4); v += __shfl_xor(v, 8);
        agg4[nt][r] = v;
      }
    if (lr == 0) {
      #pragma unroll
      for (int nt = 0; nt < 4; ++nt)
        *(floatx4*)&redagg[wave][nt * 16 + (g << 2)] = agg4[nt];
    }
    dp0 += __shfl_xor(dp0, 1); dp0 += __shfl_xor(dp0, 2); dp0 += __shfl_xor(dp0, 4); dp0 += __shfl_xor(dp0, 8);
    dp1 += __shfl_xor(dp1, 1); dp1 += __shfl_xor(dp1, 2); dp1 += __shfl_xor(dp1, 4); dp1 += __shfl_xor(dp1, 8);
    dp2 += __shfl_xor(dp2, 1); dp2 += __shfl_xor(dp2, 2); dp2 += __shfl_xor(dp2, 4); dp2 += __shfl_xor(dp2, 8);
    if (lane == 0) { sdel[wave][0] = dp0; sdel[wave][1] = dp1; sdel[wave][2] = dp2; }
    __syncthreads();
    if (tid < 64)
      agg_parts[half * 65536 + i0 * 64 + tid] =
          redagg[0][tid] + redagg[1][tid] + redagg[2][tid] + redagg[3][tid];
    else if (tid < 67) {
      int d = tid - 64;
      delta_parts[half * 3072 + i0 * 3 + d] =
          sdel[0][d] + sdel[1][d] + sdel[2][d] + sdel[3][d];
    }
}

// Fused node update + x_new. 256 blocks x 256 thr; block owns 4 nodes.
// Computes hn1 inline (h@nw1[:,:64].T + nb1) and sums the two agg/delta halves.
__global__ __launch_bounds__(256) void node_fused_kernel(
    const float* __restrict__ h, const float* __restrict__ agg0,
    const float* __restrict__ agg1, const float* __restrict__ nw1,
    const float* __restrict__ nb1, const float* __restrict__ nw2,
    const float* __restrict__ nb2, const float* __restrict__ x,
    const float* __restrict__ delta0, const float* __restrict__ delta1,
    const float* __restrict__ Lp, float* __restrict__ outh,
    float* __restrict__ outx)
{
    __shared__ float sps[256];
    const int b = blockIdx.x, tid = threadIdx.x;
    const int gt = b * 256 + tid;
    const int i = gt >> 6, o = gt & 63;
    const float* hrow = h + i * 64;
    const float* w1a = nw1 + o * 128;
    const float* a0 = agg0 + i * 64;
    const float* a1 = agg1 + i * 64;
    const float* w1b = nw1 + o * 128 + 64;
    float acc = nb1[o];
    #pragma unroll
    for (int k = 0; k < 64; ++k) acc = fmaf(hrow[k], w1a[k], acc);
    #pragma unroll
    for (int k = 0; k < 64; ++k) acc = fmaf(a0[k] + a1[k], w1b[k], acc);
    sps[tid] = fsilu(acc);
    __syncthreads();
    const float* srow = sps + (tid & ~63);
    const float* w2row = nw2 + o * 64;
    float acc2 = h[gt] + nb2[o];
    #pragma unroll
    for (int k = 0; k < 64; ++k) acc2 = fmaf(srow[k], w2row[k], acc2);
    outh[gt] = acc2;
    if (tid < 12) {
        int ii = b * 4 + tid / 3, d = tid % 3;
        float L = Lp[0];
        float v = x[ii * 3 + d] + delta0[ii * 3 + d] + delta1[ii * 3 + d];
        outx[ii * 3 + d] = v - L * floorf(v * frcp(L));
    }
}

extern "C" void kernel_launch(void* const* d_in, const int* in_sizes, int n_in,
                              void* d_out, int out_size, void* d_ws, size_t ws_size,
                              hipStream_t stream) {
    const float* h   = (const float*)d_in[0];
    const float* x   = (const float*)d_in[1];
    const float* Lp  = (const float*)d_in[2];
    const float* ew1 = (const float*)d_in[3];
    const float* eb1 = (const float*)d_in[4];
    const float* ew2 = (const float*)d_in[5];
    const float* eb2 = (const float*)d_in[6];
    const float* nw1 = (const float*)d_in[7];
    const float* nb1 = (const float*)d_in[8];
    const float* nw2 = (const float*)d_in[9];
    const float* nb2 = (const float*)d_in[10];
    const float* chw = (const float*)d_in[11];
    const float* chb = (const float*)d_in[12];
    const float* cww = (const float*)d_in[13];
    const float* aw  = (const float*)d_in[14];
    const float* ab  = (const float*)d_in[15];

    float* ws     = (float*)d_ws;
    float* ha     = ws;              // 65536
    float* hb     = ws + 65536;      // 65536
    float* agg0   = ws + 131072;     // 65536
    float* agg1   = ws + 196608;     // 65536
    float* delta0 = ws + 262144;     // 3072
    float* delta1 = ws + 265216;     // 3072

    float* outh = (float*)d_out;     // 65536
    float* outx = outh + 65536;      // 3072

    precompute_kernel<<<512, 256, 0, stream>>>(h, ew1, eb1, ha, hb);
    edge_mfma_kernel<<<2048, 256, 0, stream>>>(x, Lp, ha, hb, ew1, ew2, eb2, chw, chb,
                                               aw, ab, cww, ws + 131072, ws + 262144);
    node_fused_kernel<<<256, 256, 0, stream>>>(h, agg0, agg1, nw1, nb1, nw2, nb2, x,
                                               delta0, delta1, Lp, outh, outx);
}

// Round 14
// 90.394 us; speedup vs baseline: 3.2093x; 1.0042x over previous
//
#include <hip/hip_runtime.h>

#define Nn 1024

typedef __attribute__((ext_vector_type(8))) short short8v;
typedef __attribute__((ext_vector_type(4))) float floatx4;

// hardware-rate reciprocal / sqrt (v_rcp_f32 / v_sqrt_f32, ~1ulp).
__device__ __forceinline__ float frcp(float v)  { return __builtin_amdgcn_rcpf(v); }
__device__ __forceinline__ float fsilu(float v) { return v * frcp(1.0f + __expf(-v)); }
__device__ __forceinline__ float fsig(float v)  { return frcp(1.0f + __expf(-v)); }
__device__ __forceinline__ float ftanh10(float v){ return 10.0f - 20.0f * frcp(__expf(2.0f * v) + 1.0f); }

// 2x f32 -> packed bf16 (RNE) in ONE instruction (no builtin on gfx950 — T12)
// dst.lo16 = bf16(lo), dst.hi16 = bf16(hi)
__device__ __forceinline__ unsigned cvtpk(float lo, float hi) {
    unsigned r;
    asm("v_cvt_pk_bf16_f32 %0, %1, %2" : "=v"(r) : "v"(lo), "v"(hi));
    return r;
}

union I4S8 { int4 i; short8v s; };

// Kernel A: ha = h@Wa^T + eb1 (f32) ; hbb = bf16(h@Wb^T)
// hb feeds only the pre-silu add (T is bf16-rounded after silu anyway), so
// storing it bf16 halves its bandwidth AND halves its register footprint in
// the edge kernel (the R13 occupancy limiter: unified VGPR+AGPR total).
__global__ __launch_bounds__(256) void precompute_kernel(
    const float* __restrict__ h, const float* __restrict__ ew1,
    const float* __restrict__ eb1, float* __restrict__ ha,
    unsigned short* __restrict__ hbb)
{
    int t = blockIdx.x * 256 + threadIdx.x;   // 0 .. 2*65536-1
    int which = t >> 16;
    int rem = t & 65535;
    int i = rem >> 6, o = rem & 63;
    const float* hrow = h + i * 64;
    const float* wrow;
    float acc;
    if (which == 0) { wrow = ew1 + o * 130;      acc = eb1[o]; }
    else            { wrow = ew1 + o * 130 + 64; acc = 0.0f;   }
    #pragma unroll
    for (int k = 0; k < 64; ++k) acc = fmaf(hrow[k], wrow[k], acc);
    if (which == 0) ha[rem]  = acc;
    else            hbb[rem] = (unsigned short)(cvtpk(acc, acc) & 0xffffu);
}

// Edge pipeline. 2048 blocks x 256 thr (4 waves): block b owns node b>>1 and
// j-half b&1; wave owns 128 j's in 8 chunks of 16. R13 body with two register
// cuts: (1) hb loaded as bf16 int4 pairs (16 regs vs 32 for the two chunk
// buffers), (2) Pq/ef fused per kt2 (peak 12 vs 16). Target: unified
// VGPR+AGPR total <= 128 -> 4 waves/SIMD (R10-R13 were stuck at ~3 because
// AGPR allocation doesn't show in VGPR_Count but counts against the file).
// waves_per_eu(4,8): pin the 128-reg budget.
__global__ __launch_bounds__(256) __attribute__((amdgpu_waves_per_eu(4, 8)))
void edge_mfma_kernel(
    const float* __restrict__ x, const float* __restrict__ Lp,
    const float* __restrict__ ha, const unsigned short* __restrict__ hbb,
    const float* __restrict__ ew1, const float* __restrict__ ew2,
    const float* __restrict__ eb2, const float* __restrict__ chw,
    const float* __restrict__ chb, const float* __restrict__ aw,
    const float* __restrict__ ab, const float* __restrict__ cww,
    float* __restrict__ agg_parts, float* __restrict__ delta_parts)
{
    __shared__ __align__(16) int4 Wlds[1024];     // [w2|wc][kt][nt][lane] packed bf16 frags, 16KB
    __shared__ __align__(16) float cvec[384];     // eb2|aw|chb|cww|ha_row|wr_row (64 each)
    __shared__ float redagg[4][64];
    __shared__ float sdel[4][3];

    const int tid  = threadIdx.x;
    const int wave = tid >> 6, lane = tid & 63;
    const int lr = lane & 15, g = lane >> 4;
    const int i0 = blockIdx.x >> 1;
    const int half = blockIdx.x & 1;
    const int jbase = half * 512 + wave * 128;
    const int ghi  = g >> 1;
    const int selA = (lr + ((g & 1) << 5)) << 2;   // bpermute byte addr
    const int selB = selA + 64;
    const int4* WldsF = &Wlds[0];

    // wave 0 stages packed weight fragments into LDS: row n = lane&15, k 8-contig per g.
    if (wave == 0) {
      #pragma unroll
      for (int kt = 0; kt < 2; ++kt)
        #pragma unroll
        for (int nt = 0; nt < 4; ++nt) {
          int n = nt * 16 + lr;
          int k0 = kt * 32 + g * 8;
          float4 lo = *(const float4*)(ew2 + n * 64 + k0);
          float4 hi = *(const float4*)(ew2 + n * 64 + k0 + 4);
          Wlds[(kt * 4 + nt) * 64 + lane] = make_int4(
              (int)cvtpk(lo.x, lo.y), (int)cvtpk(lo.z, lo.w),
              (int)cvtpk(hi.x, hi.y), (int)cvtpk(hi.z, hi.w));
          lo = *(const float4*)(chw + n * 64 + k0);
          hi = *(const float4*)(chw + n * 64 + k0 + 4);
          Wlds[512 + (kt * 4 + nt) * 64 + lane] = make_int4(
              (int)cvtpk(lo.x, lo.y), (int)cvtpk(lo.z, lo.w),
              (int)cvtpk(hi.x, hi.y), (int)cvtpk(hi.z, hi.w));
        }
    }
    // constant vectors -> LDS (re-read per chunk; keeps them out of registers)
    if (tid < 64) {
      cvec[tid]       = eb2[tid];
      cvec[64 + tid]  = aw[tid];
      cvec[128 + tid] = chb[tid];
      cvec[192 + tid] = cww[tid];
      cvec[256 + tid] = ha[i0 * 64 + tid];
      cvec[320 + tid] = ew1[tid * 130 + 128] + ew1[tid * 130 + 129];
    }

    const float L = Lp[0], invL = frcp(L);
    const float ab0 = ab[0];

    floatx4 agg4[4];
    #pragma unroll
    for (int nt = 0; nt < 4; ++nt) agg4[nt] = (floatx4){0.f, 0.f, 0.f, 0.f};
    float dp0 = 0.f, dp1 = 0.f, dp2 = 0.f;

    __syncthreads();

    const float xi0 = x[i0 * 3 + 0], xi1 = x[i0 * 3 + 1], xi2 = x[i0 * 3 + 2];

    // prefetch bf16 hb fragment rows for chunk 0 (this lane's edge row lr)
    int4 hpre0, hpre1;
    {
      const unsigned short* hn = hbb + (jbase + lr) * 64 + g * 8;
      hpre0 = *(const int4*)(hn);        // channels kt=0: g*8 .. +7
      hpre1 = *(const int4*)(hn + 32);   // channels kt=1: 32+g*8 .. +7
    }

    for (int jc = 0; jc < 8; ++jc) {
      // laundered indices: keep per-chunk LDS reads opaque to LICM
      unsigned lidx = (unsigned)lane;
      asm volatile("" : "+v"(lidx));
      unsigned cb = (unsigned)(g << 4);          // g*4 floats (bias vectors)
      asm volatile("" : "+v"(cb));
      unsigned hbo = (unsigned)(g << 5);         // g*8 floats (ha/wr rows)
      asm volatile("" : "+v"(hbo));
      const float* cvp = (const float*)((const char*)cvec + cb);
      const float* hvp = (const float*)((const char*)cvec + 1024 + hbo);

      int4 hc0 = hpre0, hc1 = hpre1;
      if (jc < 7) {   // issue next chunk's hb loads NOW; latency hides under compute
        const unsigned short* hn = hbb + (jbase + (jc + 1) * 16 + lr) * 64 + g * 8;
        hpre0 = *(const int4*)(hn);
        hpre1 = *(const int4*)(hn + 32);
      }

      // ---- geometry for own edge (i0, j): all lanes, row = lr (x is L1-hot) ----
      const int j = jbase + jc * 16 + lr;
      float xd0 = xi0 - x[j * 3 + 0];
      float xd1 = xi1 - x[j * 3 + 1];
      float xd2 = xi2 - x[j * 3 + 2];
      float d0 = xd0 - L * floorf(fmaf(xd0, invL, 0.5f));
      float d1 = xd1 - L * floorf(fmaf(xd1, invL, 0.5f));
      float d2 = xd2 - L * floorf(fmaf(xd2, invL, 0.5f));
      float radial = d0 * d0 + d1 * d1 + d2 * d2;
      float cinv = frcp(__builtin_amdgcn_sqrtf(radial + 1e-8f) + 1.0f);
      float dx0 = d0 * cinv, dx1 = d1 * cinv, dx2 = d2 * cinv;

      // ---- build T fragment in registers: silu(ha + hb + radial*wr) -> bf16 ----
      short8v tf[2];
      #pragma unroll
      for (int kt = 0; kt < 2; ++kt) {
        const int4 u = kt ? hc1 : hc0;
        unsigned uw[4] = {(unsigned)u.x, (unsigned)u.y, (unsigned)u.z, (unsigned)u.w};
        floatx4 ha0 = *(const floatx4*)(hvp + kt * 32);
        floatx4 ha1 = *(const floatx4*)(hvp + kt * 32 + 4);
        floatx4 wr0 = *(const floatx4*)(hvp + 64 + kt * 32);
        floatx4 wr1 = *(const floatx4*)(hvp + 64 + kt * 32 + 4);
        float hAv[8] = {ha0[0], ha0[1], ha0[2], ha0[3], ha1[0], ha1[1], ha1[2], ha1[3]};
        float wAv[8] = {wr0[0], wr0[1], wr0[2], wr0[3], wr1[0], wr1[1], wr1[2], wr1[3]};
        union { short8v s; unsigned q[4]; } pk;
        #pragma unroll
        for (int w = 0; w < 4; ++w) {
          float fa = __uint_as_float(uw[w] << 16);          // channel 2w
          float fb = __uint_as_float(uw[w] & 0xffff0000u);  // channel 2w+1
          float pa = fsilu(fmaf(radial, wAv[2 * w],     hAv[2 * w])     + fa);
          float pb = fsilu(fmaf(radial, wAv[2 * w + 1], hAv[2 * w + 1]) + fb);
          pk.q[w] = cvtpk(pa, pb);
        }
        tf[kt] = pk.s;
      }

      // ---- GEMM1 (swapped): D1^T = ew2 * T^T ; C-init = eb2 (from LDS) ----
      floatx4 acc[4];
      #pragma unroll
      for (int nt = 0; nt < 4; ++nt) acc[nt] = *(const floatx4*)(cvp + nt * 16);
      #pragma unroll
      for (int kt = 0; kt < 2; ++kt)
        #pragma unroll
        for (int nt = 0; nt < 4; ++nt) {
          I4S8 wv; wv.i = WldsF[(kt * 4 + nt) * 64 + lidx];
          acc[nt] = __builtin_amdgcn_mfma_f32_16x16x32_bf16(wv.s, tf[kt], acc[nt], 0, 0, 0);
        }

      // ---- epilogue 1: silu, att (row-dot over n) ----
      float p = 0.f;
      #pragma unroll
      for (int nt = 0; nt < 4; ++nt) {
        floatx4 awv = *(const floatx4*)(cvp + 64 + nt * 16);
        #pragma unroll
        for (int r = 0; r < 4; ++r) {
          float s = fsilu(acc[nt][r]);
          acc[nt][r] = s;
          p = fmaf(s, awv[r], p);
        }
      }
      p += __shfl_xor(p, 16); p += __shfl_xor(p, 32);
      const float att = fsig(p + ab0);

      // ---- e = s*att, agg accum, bf16-pack, bpermute to E^T frags (fused per kt2) ----
      union { short8v s; int u[4]; } ef[2];
      #pragma unroll
      for (int kt2 = 0; kt2 < 2; ++kt2) {
        unsigned PqA[2], PqB[2];
        {
          int nt = kt2 * 2;
          float e0 = acc[nt][0] * att, e1 = acc[nt][1] * att;
          float e2 = acc[nt][2] * att, e3 = acc[nt][3] * att;
          agg4[nt][0] += e0; agg4[nt][1] += e1;
          agg4[nt][2] += e2; agg4[nt][3] += e3;
          PqA[0] = cvtpk(e0, e1); PqA[1] = cvtpk(e2, e3);
          nt = kt2 * 2 + 1;
          e0 = acc[nt][0] * att; e1 = acc[nt][1] * att;
          e2 = acc[nt][2] * att; e3 = acc[nt][3] * att;
          agg4[nt][0] += e0; agg4[nt][1] += e1;
          agg4[nt][2] += e2; agg4[nt][3] += e3;
          PqB[0] = cvtpk(e0, e1); PqB[1] = cvtpk(e2, e3);
        }
        #pragma unroll
        for (int w = 0; w < 4; ++w) {
          int sel = (w < 2) ? selA : selB;
          int v0 = __builtin_amdgcn_ds_bpermute(sel, (int)PqA[w & 1]);
          int v1 = __builtin_amdgcn_ds_bpermute(sel, (int)PqB[w & 1]);
          ef[kt2].u[w] = ghi ? v1 : v0;
        }
      }

      // ---- GEMM2 (swapped): D2^T = chw * E^T ; C-init = chb (from LDS) ----
      #pragma unroll
      for (int nt = 0; nt < 4; ++nt) acc[nt] = *(const floatx4*)(cvp + 128 + nt * 16);
      #pragma unroll
      for (int kt2 = 0; kt2 < 2; ++kt2)
        #pragma unroll
        for (int nt = 0; nt < 4; ++nt) {
          I4S8 wv; wv.i = WldsF[512 + (kt2 * 4 + nt) * 64 + lidx];
          acc[nt] = __builtin_amdgcn_mfma_f32_16x16x32_bf16(wv.s, ef[kt2].s, acc[nt], 0, 0, 0);
        }

      // ---- epilogue 2: silu, cww-dot, tanh, delta ----
      float q = 0.f;
      #pragma unroll
      for (int nt = 0; nt < 4; ++nt) {
        floatx4 cwv = *(const floatx4*)(cvp + 192 + nt * 16);
        #pragma unroll
        for (int r = 0; r < 4; ++r)
          q = fmaf(fsilu(acc[nt][r]), cwv[r], q);
      }
      q += __shfl_xor(q, 16); q += __shfl_xor(q, 32);
      const float wvv = ftanh10(q);
      if (g == 0) {
        dp0 = fmaf(dx0, wvv, dp0);
        dp1 = fmaf(dx1, wvv, dp1);
        dp2 = fmaf(dx2, wvv, dp2);
      }
    }

    // ---- final reductions: reduce over edge rows (lr) within wave ----
    #pragma unroll
    for (int nt = 0; nt < 4; ++nt)
      #pragma unroll
      for (int r = 0; r < 4; ++r) {
        float v = agg4[nt][r];
        v += __shfl_xor(v, 1); v += __shfl_xor(v, 2);
        v += __shfl_xor(v, 4); v += __shfl_xor(v, 8);
        agg4[nt][r] = v;
      }
    if (lr == 0) {
      #pragma unroll
      for (int nt = 0; nt < 4; ++nt)
        *(floatx4*)&redagg[wave][nt * 16 + (g << 2)] = agg4[nt];
    }
    dp0 += __shfl_xor(dp0, 1); dp0 += __shfl_xor(dp0, 2); dp0 += __shfl_xor(dp0, 4); dp0 += __shfl_xor(dp0, 8);
    dp1 += __shfl_xor(dp1, 1); dp1 += __shfl_xor(dp1, 2); dp1 += __shfl_xor(dp1, 4); dp1 += __shfl_xor(dp1, 8);
    dp2 += __shfl_xor(dp2, 1); dp2 += __shfl_xor(dp2, 2); dp2 += __shfl_xor(dp2, 4); dp2 += __shfl_xor(dp2, 8);
    if (lane == 0) { sdel[wave][0] = dp0; sdel[wave][1] = dp1; sdel[wave][2] = dp2; }
    __syncthreads();
    if (tid < 64)
      agg_parts[half * 65536 + i0 * 64 + tid] =
          redagg[0][tid] + redagg[1][tid] + redagg[2][tid] + redagg[3][tid];
    else if (tid < 67) {
      int d = tid - 64;
      delta_parts[half * 3072 + i0 * 3 + d] =
          sdel[0][d] + sdel[1][d] + sdel[2][d] + sdel[3][d];
    }
}

// Fused node update + x_new. 256 blocks x 256 thr; block owns 4 nodes.
// Computes hn1 inline (h@nw1[:,:64].T + nb1) and sums the two agg/delta halves.
__global__ __launch_bounds__(256) void node_fused_kernel(
    const float* __restrict__ h, const float* __restrict__ agg0,
    const float* __restrict__ agg1, const float* __restrict__ nw1,
    const float* __restrict__ nb1, const float* __restrict__ nw2,
    const float* __restrict__ nb2, const float* __restrict__ x,
    const float* __restrict__ delta0, const float* __restrict__ delta1,
    const float* __restrict__ Lp, float* __restrict__ outh,
    float* __restrict__ outx)
{
    __shared__ float sps[256];
    const int b = blockIdx.x, tid = threadIdx.x;
    const int gt = b * 256 + tid;
    const int i = gt >> 6, o = gt & 63;
    const float* hrow = h + i * 64;
    const float* w1a = nw1 + o * 128;
    const float* a0 = agg0 + i * 64;
    const float* a1 = agg1 + i * 64;
    const float* w1b = nw1 + o * 128 + 64;
    float acc = nb1[o];
    #pragma unroll
    for (int k = 0; k < 64; ++k) acc = fmaf(hrow[k], w1a[k], acc);
    #pragma unroll
    for (int k = 0; k < 64; ++k) acc = fmaf(a0[k] + a1[k], w1b[k], acc);
    sps[tid] = fsilu(acc);
    __syncthreads();
    const float* srow = sps + (tid & ~63);
    const float* w2row = nw2 + o * 64;
    float acc2 = h[gt] + nb2[o];
    #pragma unroll
    for (int k = 0; k < 64; ++k) acc2 = fmaf(srow[k], w2row[k], acc2);
    outh[gt] = acc2;
    if (tid < 12) {
        int ii = b * 4 + tid / 3, d = tid % 3;
        float L = Lp[0];
        float v = x[ii * 3 + d] + delta0[ii * 3 + d] + delta1[ii * 3 + d];
        outx[ii * 3 + d] = v - L * floorf(v * frcp(L));
    }
}

extern "C" void kernel_launch(void* const* d_in, const int* in_sizes, int n_in,
                              void* d_out, int out_size, void* d_ws, size_t ws_size,
                              hipStream_t stream) {
    const float* h   = (const float*)d_in[0];
    const float* x   = (const float*)d_in[1];
    const float* Lp  = (const float*)d_in[2];
    const float* ew1 = (const float*)d_in[3];
    const float* eb1 = (const float*)d_in[4];
    const float* ew2 = (const float*)d_in[5];
    const float* eb2 = (const float*)d_in[6];
    const float* nw1 = (const float*)d_in[7];
    const float* nb1 = (const float*)d_in[8];
    const float* nw2 = (const float*)d_in[9];
    const float* nb2 = (const float*)d_in[10];
    const float* chw = (const float*)d_in[11];
    const float* chb = (const float*)d_in[12];
    const float* cww = (const float*)d_in[13];
    const float* aw  = (const float*)d_in[14];
    const float* ab  = (const float*)d_in[15];

    float* ws = (float*)d_ws;
    float*          ha     = ws;                         // 65536 f32
    unsigned short* hbb    = (unsigned short*)(ws + 65536); // 65536 u16 = 32768 f32 slots
    float*          agg0   = ws + 98304;                 // 65536
    float*          agg1   = ws + 163840;                // 65536
    float*          delta0 = ws + 229376;                // 3072
    float*          delta1 = ws + 232448;                // 3072

    float* outh = (float*)d_out;     // 65536
    float* outx = outh + 65536;      // 3072

    precompute_kernel<<<512, 256, 0, stream>>>(h, ew1, eb1, ha, hbb);
    edge_mfma_kernel<<<2048, 256, 0, stream>>>(x, Lp, ha, hbb, ew1, ew2, eb2, chw, chb,
                                               aw, ab, cww, agg0, delta0);
    node_fused_kernel<<<256, 256, 0, stream>>>(h, agg0, agg1, nw1, nb1, nw2, nb2, x,
                                               delta0, delta1, Lp, outh, outx);
}